// Round 6
// baseline (415.444 us; speedup 1.0000x reference)
//
#include <hip/hip_runtime.h>
#include <hip/hip_bf16.h>

// ---------------------------------------------------------------------------
// RelativeMultiHeadAttention: B=2, L=2048, D=1024, H=16, d=64, MAX_REL=512
// Inputs fp32 (auto-detected vs bf16). Internals bf16 MFMA + fp32 accum.
//
// v14 = v13 structure (DMA dbuf K/V, 1 barrier/iter) + 2 i-tiles per wave:
//   - block covers 128 q-rows (wave w owns iw_base=I0+w*32 and +16);
//     grid (16,32)=512 blocks = 2/CU < LDS cap 3 -> NO quantization penalty
//     (v13's loss: 4 blocks/CU of work vs cap 3 -> ragged 2-round exec).
//   - each staged 64-row K/V tile feeds 2x MFMA work: barrier+DMA cost per
//     FLOP halves; K/V HBM re-fetch halves (512 vs 1024 blocks).
//   - v13's per-wave efficiency was 1.09x v9's; this keeps it and fixes
//     the occupancy mechanics.
// All non-attn kernels byte-identical to v12/v13.
// History: v9 141.7us (4 blk/CU) / v13 173.9us (3-cap, quantized).
// ---------------------------------------------------------------------------

typedef __attribute__((ext_vector_type(8))) short short8;   // 8 x bf16 frag
typedef __attribute__((ext_vector_type(4))) float floatx4;

#define L_SEQ 2048
#define D_MODEL 1024
#define NHEAD 16
#define DH 64
#define BH 32           // B*H
#define MROWS 4096      // B*L

__device__ inline float b2f(short s) {
    unsigned int u = ((unsigned int)(unsigned short)s) << 16;
    float f; __builtin_memcpy(&f, &u, 4); return f;
}
__device__ inline short f2b(float f) {
    unsigned int u; __builtin_memcpy(&u, &f, 4);
    u += 0x7fffu + ((u >> 16) & 1u);   // round-to-nearest-even
    return (short)(u >> 16);
}
// packed f32x2 -> bf16x2 (v_cvt_pk_bf16_f32 on gfx950)
__device__ inline unsigned int pack2(float a, float b) {
    __hip_bfloat162 h = __float22bfloat162_rn(make_float2(a, b));
    unsigned int u; __builtin_memcpy(&u, &h, 4); return u;
}
// alias-safe 4B store into a short-typed LDS array (ds_write_b32)
__device__ inline void st2(short* p, unsigned int v) {
    __builtin_memcpy(p, &v, 4);
}
// async global->LDS, 16B per lane; lds base must be wave-uniform
__device__ inline void async_cp16(short* lds, const short* g) {
    __builtin_amdgcn_global_load_lds(
        (const __attribute__((address_space(1))) unsigned int*)g,
        (__attribute__((address_space(3))) unsigned int*)lds, 16, 0, 0);
}

// ---------------------------------------------------------------------------
// dtype detector: count bf16 inf/nan exponent patterns in first 64K shorts.
// ---------------------------------------------------------------------------
__global__ __launch_bounds__(256) void detect_dtype(
        const unsigned short* __restrict__ q, int* __restrict__ flag) {
    __shared__ int s[256];
    int tid = threadIdx.x, cnt = 0;
    for (int i = tid; i < 65536; i += 256)
        if ((q[i] & 0x7F80u) == 0x7F80u) cnt++;
    s[tid] = cnt; __syncthreads();
    for (int st = 128; st; st >>= 1) {
        if (tid < st) s[tid] += s[tid + st];
        __syncthreads();
    }
    if (tid == 0) *flag = (s[0] > 4) ? 1 : 0;   // 1 = inputs are fp32
}

// ---------------------------------------------------------------------------
// Canonicalize small tensors: 4 biases -> fp32[4096], rel_emb -> bf16[65600]
// ---------------------------------------------------------------------------
__global__ __launch_bounds__(256) void norm_small(
        const void* __restrict__ bq, const void* __restrict__ bk,
        const void* __restrict__ bv, const void* __restrict__ bo,
        const void* __restrict__ rel, float* __restrict__ bias4,
        short* __restrict__ relb, const int* __restrict__ flagp) {
    const int f32 = *flagp;
    int t = blockIdx.x * 256 + threadIdx.x;
    if (t < 4096) {
        const void* src = (t < 1024) ? bq : (t < 2048) ? bk : (t < 3072) ? bv : bo;
        int i = t & 1023;
        bias4[t] = f32 ? ((const float*)src)[i] : b2f(((const short*)src)[i]);
    } else if (t < 4096 + 65600) {
        int i = t - 4096;
        relb[i] = f32 ? f2b(((const float*)rel)[i]) : ((const short*)rel)[i];
    }
}

// ---------------------------------------------------------------------------
// Weight transpose: 4 x (1024,1024) (c,n) -> bf16 (n,c)
// ---------------------------------------------------------------------------
__global__ __launch_bounds__(256) void transpose4(
        const void* __restrict__ w0, const void* __restrict__ w1,
        const void* __restrict__ w2, const void* __restrict__ w3,
        short* __restrict__ dst, const int* __restrict__ flagp) {
    const int f32 = *flagp;
    __shared__ short tile[32][33];
    const void* src = (blockIdx.z == 0) ? w0 : (blockIdx.z == 1) ? w1
                    : (blockIdx.z == 2) ? w2 : w3;
    short* d = dst + (size_t)blockIdx.z * (D_MODEL * D_MODEL);
    int x = blockIdx.x * 32 + threadIdx.x;   // n
    int y0 = blockIdx.y * 32;                // c base
    for (int yy = threadIdx.y; yy < 32; yy += 8) {
        size_t idx = (size_t)(y0 + yy) * D_MODEL + x;
        tile[yy][threadIdx.x] = f32 ? f2b(((const float*)src)[idx])
                                    : ((const short*)src)[idx];
    }
    __syncthreads();
    int x0 = blockIdx.x * 32;
    for (int yy = threadIdx.y; yy < 32; yy += 8)
        d[(size_t)(x0 + yy) * D_MODEL + y0 + threadIdx.x] = tile[threadIdx.x][yy];
}

// ---------------------------------------------------------------------------
// convert3: fp32 Q/K/V inputs -> canonical bf16 (memory-bound, ~15us).
// ---------------------------------------------------------------------------
__global__ __launch_bounds__(256) void convert3(
        const float* __restrict__ q, const float* __restrict__ k,
        const float* __restrict__ v, short* __restrict__ abf_q,
        short* __restrict__ abf_k, short* __restrict__ abf_v,
        const int* __restrict__ flagp) {
    if (!*flagp) return;
    const int z = blockIdx.y;
    const float* src = (z == 0) ? q : (z == 1) ? k : v;
    short* dst = (z == 0) ? abf_q : (z == 1) ? abf_k : abf_v;
    size_t i8 = ((size_t)blockIdx.x * 256 + threadIdx.x) * 8;
    float4 f0 = *(const float4*)(&src[i8]);
    float4 f1 = *(const float4*)(&src[i8 + 4]);
    uint4 s;
    s.x = pack2(f0.x, f0.y); s.y = pack2(f0.z, f0.w);
    s.z = pack2(f1.x, f1.y); s.w = pack2(f1.z, f1.w);
    *(uint4*)(&dst[i8]) = s;
}

// ---------------------------------------------------------------------------
// Fused QKV projection GEMM: z = 0,1,2.  C = A(4096,1024) @ WT^T + bias.
// A and B both bf16 -> global_load_lds width 16 (m97 layout, stride-32 rows).
// z 0/1 -> (b,h,l,d) bf16; z=2 -> (b,h,d,l) bf16 (V^T).
// ---------------------------------------------------------------------------
__global__ __launch_bounds__(256) void proj_gemm(
        const void* __restrict__ Aq, const void* __restrict__ Ak,
        const void* __restrict__ Av, const short* __restrict__ Cq,
        const short* __restrict__ Ck, const short* __restrict__ Cv,
        const short* __restrict__ WT, const float* __restrict__ bias4,
        short* __restrict__ Qout, const int* __restrict__ flagp) {
    const int f32 = *flagp;
    const int z = blockIdx.z;
    // A source: converted bf16 scratch when inputs were fp32, else originals
    const short* A_ = f32 ? ((z == 0) ? Cq : (z == 1) ? Ck : Cv)
                          : (const short*)((z == 0) ? Aq : (z == 1) ? Ak : Av);
    const short* BT = WT + (size_t)z * (D_MODEL * D_MODEL);
    const float* bias = bias4 + z * 1024;
    short* C = Qout + (size_t)z * ((size_t)MROWS * D_MODEL);
    const int K = D_MODEL;

    __shared__ short Alds[128 * 32];
    __shared__ short Blds[128 * 32];
    const int tid = threadIdx.x;
    const int w = tid >> 6, lane = tid & 63, cl = lane & 15, quad = lane >> 4;
    const int wr = w >> 1, wc = w & 1;
    const int m0 = blockIdx.y * 128, n0 = blockIdx.x * 128;
    const int grow = lane >> 2, gcol = (lane & 3) * 8;   // async staging map

    floatx4 acc[4][4];
    for (int i = 0; i < 4; i++)
        for (int j = 0; j < 4; j++)
            acc[i][j] = {0.f, 0.f, 0.f, 0.f};

    for (int k0 = 0; k0 < K; k0 += 32) {
        // A and B: async direct-to-LDS (wave-uniform base + lane*16B)
        for (int s = 0; s < 2; s++) {
            int r = w * 32 + s * 16;
            async_cp16(&Blds[r * 32], &BT[(size_t)(n0 + r + grow) * K + k0 + gcol]);
            async_cp16(&Alds[r * 32], &A_[(size_t)(m0 + r + grow) * K + k0 + gcol]);
        }
        __syncthreads();

        short8 af[4], bfr[4];
        for (int mt = 0; mt < 4; mt++)
            af[mt] = *(const short8*)(&Alds[(wr * 64 + mt * 16 + cl) * 32 + quad * 8]);
        for (int nt = 0; nt < 4; nt++)
            bfr[nt] = *(const short8*)(&Blds[(wc * 64 + nt * 16 + cl) * 32 + quad * 8]);
        for (int mt = 0; mt < 4; mt++)
            for (int nt = 0; nt < 4; nt++)
                acc[mt][nt] = __builtin_amdgcn_mfma_f32_16x16x32_bf16(
                    af[mt], bfr[nt], acc[mt][nt], 0, 0, 0);
        __syncthreads();
    }

    for (int nt = 0; nt < 4; nt++) {
        int n = n0 + wc * 64 + nt * 16 + cl;
        float bv = bias[n];
        int h = n >> 6, d = n & 63;
        for (int mt = 0; mt < 4; mt++) {
            for (int r = 0; r < 4; r++) {
                int m = m0 + wr * 64 + mt * 16 + quad * 4 + r;
                float v = acc[mt][nt][r] + bv;
                int b = m >> 11, i = m & 2047;
                if (z < 2)
                    C[(((size_t)(b * NHEAD + h)) * L_SEQ + i) * DH + d] = f2b(v);
                else
                    C[(((size_t)(b * NHEAD + h)) * DH + d) * L_SEQ + i] = f2b(v);
            }
        }
    }
}

// ---------------------------------------------------------------------------
// Output GEMM: C(4096,1024) = A @ WT^T + bias.  128x64 tile, full async.
// ---------------------------------------------------------------------------
__global__ __launch_bounds__(256) void out_gemm(
        const short* __restrict__ A, const short* __restrict__ BT,
        const float* __restrict__ bias, void* __restrict__ C_,
        const int* __restrict__ flagp) {
    const int f32 = *flagp;
    const int K = D_MODEL, N = D_MODEL;
    __shared__ short Alds[128 * 32];
    __shared__ short Blds[64 * 32];
    const int tid = threadIdx.x;
    const int w = tid >> 6, lane = tid & 63, cl = lane & 15, quad = lane >> 4;
    const int wr = w >> 1, wc = w & 1;
    const int m0 = blockIdx.y * 128, n0 = blockIdx.x * 64;
    const int grow = lane >> 2, gcol = (lane & 3) * 8;

    floatx4 acc[4][2];
    for (int i = 0; i < 4; i++)
        for (int j = 0; j < 2; j++)
            acc[i][j] = {0.f, 0.f, 0.f, 0.f};

    for (int k0 = 0; k0 < K; k0 += 32) {
        for (int s = 0; s < 2; s++) {
            int r = w * 32 + s * 16;
            async_cp16(&Alds[r * 32], &A[(size_t)(m0 + r + grow) * K + k0 + gcol]);
        }
        {
            int r = w * 16;
            async_cp16(&Blds[r * 32], &BT[(size_t)(n0 + r + grow) * K + k0 + gcol]);
        }
        __syncthreads();

        short8 af[4], bfr[2];
        for (int mt = 0; mt < 4; mt++)
            af[mt] = *(const short8*)(&Alds[(wr * 64 + mt * 16 + cl) * 32 + quad * 8]);
        for (int nt = 0; nt < 2; nt++)
            bfr[nt] = *(const short8*)(&Blds[(wc * 32 + nt * 16 + cl) * 32 + quad * 8]);
        for (int mt = 0; mt < 4; mt++)
            for (int nt = 0; nt < 2; nt++)
                acc[mt][nt] = __builtin_amdgcn_mfma_f32_16x16x32_bf16(
                    af[mt], bfr[nt], acc[mt][nt], 0, 0, 0);
        __syncthreads();
    }

    for (int nt = 0; nt < 2; nt++) {
        int n = n0 + wc * 32 + nt * 16 + cl;
        float bv = bias[n];
        for (int mt = 0; mt < 4; mt++) {
            for (int r = 0; r < 4; r++) {
                int m = m0 + wr * 64 + mt * 16 + quad * 4 + r;
                float v = acc[mt][nt][r] + bv;
                if (f32) ((float*)C_)[(size_t)m * N + n] = v;
                else     ((short*)C_)[(size_t)m * N + n] = f2b(v);
            }
        }
    }
}

// ---------------------------------------------------------------------------
// Flash attention v14: DMA dbuf K/V (1 barrier/iter) + 2 i-tiles per wave.
// Block covers 128 q-rows; grid (16,32)=512 blocks = 2 blocks/CU (< cap 3).
// TBAA-safe LDS stores (st2/memcpy). 52 KB LDS.
// ---------------------------------------------------------------------------
__global__ __launch_bounds__(256) void attn_kernel(
        const short* __restrict__ Q, const short* __restrict__ K,
        const short* __restrict__ VT, const short* __restrict__ rel,
        short* __restrict__ out) {
    const int tid = threadIdx.x;
    const int w = tid >> 6, lane = tid & 63, cl = lane & 15, quad = lane >> 4;
    const int bh = blockIdx.y, b = bh >> 4, h = bh & 15;
    const int I0 = blockIdx.x * 128;
    const int iw_base = I0 + w * 32;    // wave covers rows iw_base..iw_base+31

    const short* Qp = Q + (size_t)bh * L_SEQ * DH;
    const short* Kp = K + (size_t)bh * L_SEQ * DH;
    const short* Vp = VT + (size_t)bh * DH * L_SEQ;

    __shared__ short Klds2[2][64 * 64];    // dbuf, swizzled, 16KB
    __shared__ short Vtlds2[2][64 * 64];   // dbuf, swizzled, 16KB
    __shared__ short PpLds[4][16 * 86];    // per-wave pos [i][t], bf16, 10.75KB
    __shared__ short Plds[4][16 * 64];     // per-wave P, swizzled, 8KB

    short* PpW = &PpLds[w][0];
    short* PW  = &Plds[w][0];

    short8 aq[2][2];
#pragma unroll
    for (int it = 0; it < 2; it++)
        for (int c = 0; c < 2; c++)
            aq[it][c] = *(const short8*)(
                &Qp[(size_t)(iw_base + it * 16 + cl) * DH + c * 32 + quad * 8]);

    const float SCALE2 = 0.125f * 1.44269504088896340736f;  // /sqrt(64)*log2(e)
    const float FMAX = 32.0f;                               // fixed softmax shift

    // clamped-position row constants per i-tile: q_i . E[0], q_i . E[1024]
    float addlo[2], addhi[2];
#pragma unroll
    for (int it = 0; it < 2; it++) {
        floatx4 Dc = {0.f, 0.f, 0.f, 0.f};
        int eidx = (cl == 1) ? 1024 : 0;
        for (int c = 0; c < 2; c++) {
            short8 ae = *(const short8*)(&rel[(size_t)eidx * DH + c * 32 + quad * 8]);
            Dc = __builtin_amdgcn_mfma_f32_16x16x32_bf16(ae, aq[it][c], Dc, 0, 0, 0);
        }
        float pcl = __shfl(Dc[0], cl, 64);
        float pch = __shfl(Dc[1], cl, 64);
        addlo[it] = fmaf(pcl, SCALE2, -FMAX);
        addhi[it] = fmaf(pch, SCALE2, -FMAX);
    }

    floatx4 O[2][4];
#pragma unroll
    for (int it = 0; it < 2; it++)
        for (int dt = 0; dt < 4; dt++) O[it][dt] = {0.f, 0.f, 0.f, 0.f};
    float lsum0 = 0.f, lsum1 = 0.f;

    // DMA staging map: group g=w*2+s covers LDS rows g*8..g*8+7 linearly.
    // Lane l -> row r=g*8+(l>>3), slot p=l&7; source chunk c=p^(r&7).
    const int lr = lane >> 3;                    // 0..7
    const int lc8 = ((lane & 7) ^ lr) * 8;       // pre-swizzled col (shorts)

    // prologue: stage tile 0 into buf 0
    for (int s = 0; s < 2; s++) {
        int g = w * 2 + s;
        int r = g * 8 + lr;
        async_cp16(&Klds2[0][g * 512], &Kp[(size_t)r * DH + lc8]);
        async_cp16(&Vtlds2[0][g * 512], &Vp[(size_t)r * L_SEQ + lc8]);
    }
    int cur = 0;

    for (int j0 = 0; j0 < L_SEQ; j0 += 64) {
        // barrier drains DMA (vmcnt) -> buf[cur] ready; prev reads done.
        __syncthreads();

        // stage NEXT tile into the other buffer; latency hides under compute
        if (j0 + 64 < L_SEQ) {
            for (int s = 0; s < 2; s++) {
                int g = w * 2 + s;
                int r = g * 8 + lr;
                async_cp16(&Klds2[cur ^ 1][g * 512],
                           &Kp[(size_t)(j0 + 64 + r) * DH + lc8]);
                async_cp16(&Vtlds2[cur ^ 1][g * 512],
                           &Vp[(size_t)r * L_SEQ + (j0 + 64) + lc8]);
            }
        }
        const short* Kb = &Klds2[cur][0];
        const short* Vb = &Vtlds2[cur][0];

#pragma unroll
        for (int it = 0; it < 2; it++) {
            const int iw = iw_base + it * 16;
            const bool hi_clamp = (j0 - iw - 15) >= 512;
            const bool lo_clamp = (j0 + 63 - iw) <= -512;
            const bool banded = !(hi_clamp || lo_clamp);
            const float addc = hi_clamp ? addhi[it] : addlo[it];

            // --- content: S^T[j_loc][i] = K Q^T ---
            floatx4 St[4];
            for (int jt = 0; jt < 4; jt++) {
                St[jt] = {0.f, 0.f, 0.f, 0.f};
                int row = jt * 16 + cl;
                for (int c = 0; c < 2; c++) {
                    int pos = ((4 * c + quad) ^ (cl & 7)) * 8;
                    short8 bk = *(const short8*)(&Kb[row * 64 + pos]);
                    St[jt] = __builtin_amdgcn_mfma_f32_16x16x32_bf16(
                        bk, aq[it][c], St[jt], 0, 0, 0);
                }
            }

            if (banded) {
                // Pp^T[t][i], t window 0..78
                floatx4 Pt[5];
                for (int pt = 0; pt < 5; pt++) Pt[pt] = {0.f, 0.f, 0.f, 0.f};
                const int base = j0 - iw - 15;
                for (int pt = 0; pt < 5; pt++) {
                    int raw = pt * 16 + cl + base;
                    int idx = (raw < -512 ? -512 : (raw > 512 ? 512 : raw)) + 512;
                    const short* ep = rel + (size_t)idx * DH;
                    for (int c = 0; c < 2; c++) {
                        short8 be = *(const short8*)(&ep[c * 32 + quad * 8]);
                        Pt[pt] = __builtin_amdgcn_mfma_f32_16x16x32_bf16(
                            be, aq[it][c], Pt[pt], 0, 0, 0);
                    }
                }
                // store transposed [i=cl][t], packed pairs — alias-safe
                for (int pt = 0; pt < 5; pt++) {
                    int t = pt * 16 + quad * 4;
                    st2(&PpW[cl * 86 + t],     pack2(Pt[pt][0], Pt[pt][1]));
                    st2(&PpW[cl * 86 + t + 2], pack2(Pt[pt][2], Pt[pt][3]));
                }
                // wave-internal LDS RAW (memcpy stores may-alias -> ordered)
                for (int jt = 0; jt < 4; jt++)
                    for (int r = 0; r < 4; r++) {
                        int t = jt * 16 + quad * 4 + r - cl + 15;   // 0..78
                        float pos = b2f(PpW[cl * 86 + t]);
                        St[jt][r] = fmaf(St[jt][r], SCALE2, fmaf(pos, SCALE2, -FMAX));
                    }
            } else {
                for (int jt = 0; jt < 4; jt++)
                    for (int r = 0; r < 4; r++)
                        St[jt][r] = fmaf(St[jt][r], SCALE2, addc);
            }

            // --- exp2 + sum ---
            for (int jt = 0; jt < 4; jt++)
                for (int r = 0; r < 4; r++) {
                    float p = __builtin_amdgcn_exp2f(St[jt][r]);
                    St[jt][r] = p;
                    if (it == 0) lsum0 += p; else lsum1 += p;
                }

            // --- P -> per-wave LDS [i=cl][j_loc], swizzled, alias-safe ---
            for (int jt = 0; jt < 4; jt++)
                for (int pr = 0; pr < 2; pr++) {
                    int jl = jt * 16 + quad * 4 + pr * 2;
                    int addr = cl * 64 + ((jl >> 3) ^ (cl & 7)) * 8 + (jl & 7);
                    st2(&PW[addr], pack2(St[jt][2 * pr], St[jt][2 * pr + 1]));
                }

            // --- O^T += V^T P^T ---
            for (int c = 0; c < 2; c++) {
                int ppos = ((4 * c + quad) ^ (cl & 7)) * 8;
                short8 bp = *(const short8*)(&PW[cl * 64 + ppos]);
                for (int dt = 0; dt < 4; dt++) {
                    int row = dt * 16 + cl;
                    int vpos = ((4 * c + quad) ^ (cl & 7)) * 8;
                    short8 av = *(const short8*)(&Vb[row * 64 + vpos]);
                    O[it][dt] = __builtin_amdgcn_mfma_f32_16x16x32_bf16(
                        av, bp, O[it][dt], 0, 0, 0);
                }
            }
        }
        cur ^= 1;
    }

    // --- epilogue per i-tile: l reduction, O^T*inv -> bf16 transpose ---
#pragma unroll
    for (int it = 0; it < 2; it++) {
        float lsum = (it == 0) ? lsum0 : lsum1;
        lsum += __shfl_xor(lsum, 16, 64);
        lsum += __shfl_xor(lsum, 32, 64);
        float inv = 1.0f / lsum;

        for (int dt = 0; dt < 4; dt++)
            for (int pr = 0; pr < 2; pr++) {
                int jl = dt * 16 + quad * 4 + pr * 2;   // d index
                int addr = cl * 64 + ((jl >> 3) ^ (cl & 7)) * 8 + (jl & 7);
                st2(&PW[addr], pack2(O[it][dt][2 * pr] * inv,
                                     O[it][dt][2 * pr + 1] * inv));
            }
        // wave-internal; memcpy stores ordered vs short8 reads
        size_t obase = ((size_t)b * L_SEQ + iw_base + it * 16 + cl) * D_MODEL
                     + h * DH;
        for (int s = 0; s < 2; s++) {
            int c2 = quad * 2 + s;
            short8 o = *(const short8*)(&PW[cl * 64 + (c2 ^ (cl & 7)) * 8]);
            *(short8*)(&out[obase + c2 * 8]) = o;
        }
    }
}

// ---------------------------------------------------------------------------
extern "C" void kernel_launch(void* const* d_in, const int* in_sizes, int n_in,
                              void* d_out, int out_size, void* d_ws, size_t ws_size,
                              hipStream_t stream) {
    const void* query = d_in[0];
    const void* key   = d_in[1];
    const void* value = d_in[2];
    const void* wq = d_in[3];  const void* bq = d_in[4];
    const void* wk = d_in[5];  const void* bk = d_in[6];
    const void* wv = d_in[7];  const void* bv = d_in[8];
    const void* wo = d_in[9];  const void* bo = d_in[10];
    const void* rel = d_in[11];

    // v4-proven 40.2MB layout.
    int* flag = (int*)d_ws;
    short* ws = (short*)d_ws + 16;                     // 32B offset
    const size_t WSZ = (size_t)D_MODEL * D_MODEL;      // 1M elems per weight
    const size_t TSZ = (size_t)MROWS * D_MODEL;        // 4M elems per tensor
    short* WT   = ws;                                  // 4 x WSZ (q,k,v,o)
    short* Qw   = ws + 4 * WSZ;
    short* Kw   = Qw + TSZ;
    short* Vtw  = Kw + TSZ;
    short* Attw = Vtw + TSZ;
    float* bias4 = (float*)(Attw + TSZ);               // 4096 fp32
    short* relb  = (short*)(bias4 + 4096);             // 65600 bf16

    // bf16-A scratch for the f32-input path (lifetimes verified, v12).
    short* Cq = (short*)d_out;
    short* Ck = (short*)d_out + TSZ;
    short* Cv = Attw;

    detect_dtype<<<1, 256, 0, stream>>>((const unsigned short*)query, flag);
    norm_small<<<273, 256, 0, stream>>>(bq, bk, bv, bo, rel, bias4, relb, flag);
    transpose4<<<dim3(32, 32, 4), dim3(32, 8), 0, stream>>>(wq, wk, wv, wo, WT, flag);

    convert3<<<dim3(2048, 3), 256, 0, stream>>>(
        (const float*)query, (const float*)key, (const float*)value,
        Cq, Ck, Cv, flag);

    proj_gemm<<<dim3(8, 32, 3), 256, 0, stream>>>(query, key, value,
                                                  Cq, Ck, Cv, WT, bias4,
                                                  Qw, flag);

    attn_kernel<<<dim3(L_SEQ / 128, BH), 256, 0, stream>>>(Qw, Kw, Vtw, relb, Attw);

    out_gemm<<<dim3(16, 32), 256, 0, stream>>>(Attw, WT + 3 * WSZ, bias4 + 3072,
                                               d_out, flag);
}

// Round 7
// 388.138 us; speedup vs baseline: 1.0704x; 1.0704x over previous
//
#include <hip/hip_runtime.h>
#include <hip/hip_bf16.h>

// ---------------------------------------------------------------------------
// RelativeMultiHeadAttention: B=2, L=2048, D=1024, H=16, d=64, MAX_REL=512
// Inputs fp32 (auto-detected vs bf16). Internals bf16 MFMA + fp32 accum.
//
// v15 = v9-geometry attn (64 q-rows/block, 4 blocks/CU) + DMA staging that
// FITS the 40KB/block budget (lesson of v13/v14: throughput ~ resident
// waves; LDS over 40KB kills it):
//   - K double-buffered via global_load_lds (read between barriers -> dbuf
//     required); V SINGLE-buffered via DMA (overwrite legal after barrier1,
//     drained by barrier2's conservative vmcnt(0) -> latency hidden under
//     QK^T+softmax). Same 2 barriers as v9 but zero VGPR round-trip and no
//     serial load->ds_write chain.
//   - Pp/P LDS union (wave-private, strictly sequential): 18.75 -> 11KB.
//     Total 35.6KB -> 4 blocks/CU like v9.
//   - detect_dtype eliminated when in_sizes[0] identifies dtype (bytes);
//     hipMemsetAsync(flag) instead; device fallback kept if ambiguous.
// Other kernels byte-identical to v12/v14.
// History: v9 141.7us(16 waves/CU) / v13 173.9 / v14 172.2 (8 waves/CU).
// ---------------------------------------------------------------------------

typedef __attribute__((ext_vector_type(8))) short short8;   // 8 x bf16 frag
typedef __attribute__((ext_vector_type(4))) float floatx4;

#define L_SEQ 2048
#define D_MODEL 1024
#define NHEAD 16
#define DH 64
#define BH 32           // B*H
#define MROWS 4096      // B*L

__device__ inline float b2f(short s) {
    unsigned int u = ((unsigned int)(unsigned short)s) << 16;
    float f; __builtin_memcpy(&f, &u, 4); return f;
}
__device__ inline short f2b(float f) {
    unsigned int u; __builtin_memcpy(&u, &f, 4);
    u += 0x7fffu + ((u >> 16) & 1u);   // round-to-nearest-even
    return (short)(u >> 16);
}
// packed f32x2 -> bf16x2 (v_cvt_pk_bf16_f32 on gfx950)
__device__ inline unsigned int pack2(float a, float b) {
    __hip_bfloat162 h = __float22bfloat162_rn(make_float2(a, b));
    unsigned int u; __builtin_memcpy(&u, &h, 4); return u;
}
// alias-safe 4B store into a short-typed LDS array (ds_write_b32)
__device__ inline void st2(short* p, unsigned int v) {
    __builtin_memcpy(p, &v, 4);
}
// async global->LDS, 16B per lane; lds base must be wave-uniform
__device__ inline void async_cp16(short* lds, const short* g) {
    __builtin_amdgcn_global_load_lds(
        (const __attribute__((address_space(1))) unsigned int*)g,
        (__attribute__((address_space(3))) unsigned int*)lds, 16, 0, 0);
}

// ---------------------------------------------------------------------------
// dtype detector (FALLBACK ONLY): bf16 inf/nan patterns in first 64K shorts.
// ---------------------------------------------------------------------------
__global__ __launch_bounds__(256) void detect_dtype(
        const unsigned short* __restrict__ q, int* __restrict__ flag) {
    __shared__ int s[256];
    int tid = threadIdx.x, cnt = 0;
    for (int i = tid; i < 65536; i += 256)
        if ((q[i] & 0x7F80u) == 0x7F80u) cnt++;
    s[tid] = cnt; __syncthreads();
    for (int st = 128; st; st >>= 1) {
        if (tid < st) s[tid] += s[tid + st];
        __syncthreads();
    }
    if (tid == 0) *flag = (s[0] > 4) ? 1 : 0;   // 1 = inputs are fp32
}

// ---------------------------------------------------------------------------
// Canonicalize small tensors: 4 biases -> fp32[4096], rel_emb -> bf16[65600]
// ---------------------------------------------------------------------------
__global__ __launch_bounds__(256) void norm_small(
        const void* __restrict__ bq, const void* __restrict__ bk,
        const void* __restrict__ bv, const void* __restrict__ bo,
        const void* __restrict__ rel, float* __restrict__ bias4,
        short* __restrict__ relb, const int* __restrict__ flagp) {
    const int f32 = *flagp;
    int t = blockIdx.x * 256 + threadIdx.x;
    if (t < 4096) {
        const void* src = (t < 1024) ? bq : (t < 2048) ? bk : (t < 3072) ? bv : bo;
        int i = t & 1023;
        bias4[t] = f32 ? ((const float*)src)[i] : b2f(((const short*)src)[i]);
    } else if (t < 4096 + 65600) {
        int i = t - 4096;
        relb[i] = f32 ? f2b(((const float*)rel)[i]) : ((const short*)rel)[i];
    }
}

// ---------------------------------------------------------------------------
// Weight transpose: 4 x (1024,1024) (c,n) -> bf16 (n,c)
// ---------------------------------------------------------------------------
__global__ __launch_bounds__(256) void transpose4(
        const void* __restrict__ w0, const void* __restrict__ w1,
        const void* __restrict__ w2, const void* __restrict__ w3,
        short* __restrict__ dst, const int* __restrict__ flagp) {
    const int f32 = *flagp;
    __shared__ short tile[32][33];
    const void* src = (blockIdx.z == 0) ? w0 : (blockIdx.z == 1) ? w1
                    : (blockIdx.z == 2) ? w2 : w3;
    short* d = dst + (size_t)blockIdx.z * (D_MODEL * D_MODEL);
    int x = blockIdx.x * 32 + threadIdx.x;   // n
    int y0 = blockIdx.y * 32;                // c base
    for (int yy = threadIdx.y; yy < 32; yy += 8) {
        size_t idx = (size_t)(y0 + yy) * D_MODEL + x;
        tile[yy][threadIdx.x] = f32 ? f2b(((const float*)src)[idx])
                                    : ((const short*)src)[idx];
    }
    __syncthreads();
    int x0 = blockIdx.x * 32;
    for (int yy = threadIdx.y; yy < 32; yy += 8)
        d[(size_t)(x0 + yy) * D_MODEL + y0 + threadIdx.x] = tile[threadIdx.x][yy];
}

// ---------------------------------------------------------------------------
// convert3: fp32 Q/K/V inputs -> canonical bf16 (memory-bound, ~15us).
// ---------------------------------------------------------------------------
__global__ __launch_bounds__(256) void convert3(
        const float* __restrict__ q, const float* __restrict__ k,
        const float* __restrict__ v, short* __restrict__ abf_q,
        short* __restrict__ abf_k, short* __restrict__ abf_v,
        const int* __restrict__ flagp) {
    if (!*flagp) return;
    const int z = blockIdx.y;
    const float* src = (z == 0) ? q : (z == 1) ? k : v;
    short* dst = (z == 0) ? abf_q : (z == 1) ? abf_k : abf_v;
    size_t i8 = ((size_t)blockIdx.x * 256 + threadIdx.x) * 8;
    float4 f0 = *(const float4*)(&src[i8]);
    float4 f1 = *(const float4*)(&src[i8 + 4]);
    uint4 s;
    s.x = pack2(f0.x, f0.y); s.y = pack2(f0.z, f0.w);
    s.z = pack2(f1.x, f1.y); s.w = pack2(f1.z, f1.w);
    *(uint4*)(&dst[i8]) = s;
}

// ---------------------------------------------------------------------------
// Fused QKV projection GEMM: z = 0,1,2.  C = A(4096,1024) @ WT^T + bias.
// A and B both bf16 -> global_load_lds width 16 (m97 layout, stride-32 rows).
// z 0/1 -> (b,h,l,d) bf16; z=2 -> (b,h,d,l) bf16 (V^T).
// ---------------------------------------------------------------------------
__global__ __launch_bounds__(256) void proj_gemm(
        const void* __restrict__ Aq, const void* __restrict__ Ak,
        const void* __restrict__ Av, const short* __restrict__ Cq,
        const short* __restrict__ Ck, const short* __restrict__ Cv,
        const short* __restrict__ WT, const float* __restrict__ bias4,
        short* __restrict__ Qout, const int* __restrict__ flagp) {
    const int f32 = *flagp;
    const int z = blockIdx.z;
    // A source: converted bf16 scratch when inputs were fp32, else originals
    const short* A_ = f32 ? ((z == 0) ? Cq : (z == 1) ? Ck : Cv)
                          : (const short*)((z == 0) ? Aq : (z == 1) ? Ak : Av);
    const short* BT = WT + (size_t)z * (D_MODEL * D_MODEL);
    const float* bias = bias4 + z * 1024;
    short* C = Qout + (size_t)z * ((size_t)MROWS * D_MODEL);
    const int K = D_MODEL;

    __shared__ short Alds[128 * 32];
    __shared__ short Blds[128 * 32];
    const int tid = threadIdx.x;
    const int w = tid >> 6, lane = tid & 63, cl = lane & 15, quad = lane >> 4;
    const int wr = w >> 1, wc = w & 1;
    const int m0 = blockIdx.y * 128, n0 = blockIdx.x * 128;
    const int grow = lane >> 2, gcol = (lane & 3) * 8;   // async staging map

    floatx4 acc[4][4];
    for (int i = 0; i < 4; i++)
        for (int j = 0; j < 4; j++)
            acc[i][j] = {0.f, 0.f, 0.f, 0.f};

    for (int k0 = 0; k0 < K; k0 += 32) {
        // A and B: async direct-to-LDS (wave-uniform base + lane*16B)
        for (int s = 0; s < 2; s++) {
            int r = w * 32 + s * 16;
            async_cp16(&Blds[r * 32], &BT[(size_t)(n0 + r + grow) * K + k0 + gcol]);
            async_cp16(&Alds[r * 32], &A_[(size_t)(m0 + r + grow) * K + k0 + gcol]);
        }
        __syncthreads();

        short8 af[4], bfr[4];
        for (int mt = 0; mt < 4; mt++)
            af[mt] = *(const short8*)(&Alds[(wr * 64 + mt * 16 + cl) * 32 + quad * 8]);
        for (int nt = 0; nt < 4; nt++)
            bfr[nt] = *(const short8*)(&Blds[(wc * 64 + nt * 16 + cl) * 32 + quad * 8]);
        for (int mt = 0; mt < 4; mt++)
            for (int nt = 0; nt < 4; nt++)
                acc[mt][nt] = __builtin_amdgcn_mfma_f32_16x16x32_bf16(
                    af[mt], bfr[nt], acc[mt][nt], 0, 0, 0);
        __syncthreads();
    }

    for (int nt = 0; nt < 4; nt++) {
        int n = n0 + wc * 64 + nt * 16 + cl;
        float bv = bias[n];
        int h = n >> 6, d = n & 63;
        for (int mt = 0; mt < 4; mt++) {
            for (int r = 0; r < 4; r++) {
                int m = m0 + wr * 64 + mt * 16 + quad * 4 + r;
                float v = acc[mt][nt][r] + bv;
                int b = m >> 11, i = m & 2047;
                if (z < 2)
                    C[(((size_t)(b * NHEAD + h)) * L_SEQ + i) * DH + d] = f2b(v);
                else
                    C[(((size_t)(b * NHEAD + h)) * DH + d) * L_SEQ + i] = f2b(v);
            }
        }
    }
}

// ---------------------------------------------------------------------------
// Output GEMM: C(4096,1024) = A @ WT^T + bias.  128x64 tile, full async.
// ---------------------------------------------------------------------------
__global__ __launch_bounds__(256) void out_gemm(
        const short* __restrict__ A, const short* __restrict__ BT,
        const float* __restrict__ bias, void* __restrict__ C_,
        const int* __restrict__ flagp) {
    const int f32 = *flagp;
    const int K = D_MODEL, N = D_MODEL;
    __shared__ short Alds[128 * 32];
    __shared__ short Blds[64 * 32];
    const int tid = threadIdx.x;
    const int w = tid >> 6, lane = tid & 63, cl = lane & 15, quad = lane >> 4;
    const int wr = w >> 1, wc = w & 1;
    const int m0 = blockIdx.y * 128, n0 = blockIdx.x * 64;
    const int grow = lane >> 2, gcol = (lane & 3) * 8;

    floatx4 acc[4][2];
    for (int i = 0; i < 4; i++)
        for (int j = 0; j < 2; j++)
            acc[i][j] = {0.f, 0.f, 0.f, 0.f};

    for (int k0 = 0; k0 < K; k0 += 32) {
        for (int s = 0; s < 2; s++) {
            int r = w * 32 + s * 16;
            async_cp16(&Alds[r * 32], &A[(size_t)(m0 + r + grow) * K + k0 + gcol]);
        }
        {
            int r = w * 16;
            async_cp16(&Blds[r * 32], &BT[(size_t)(n0 + r + grow) * K + k0 + gcol]);
        }
        __syncthreads();

        short8 af[4], bfr[2];
        for (int mt = 0; mt < 4; mt++)
            af[mt] = *(const short8*)(&Alds[(wr * 64 + mt * 16 + cl) * 32 + quad * 8]);
        for (int nt = 0; nt < 2; nt++)
            bfr[nt] = *(const short8*)(&Blds[(wc * 32 + nt * 16 + cl) * 32 + quad * 8]);
        for (int mt = 0; mt < 4; mt++)
            for (int nt = 0; nt < 2; nt++)
                acc[mt][nt] = __builtin_amdgcn_mfma_f32_16x16x32_bf16(
                    af[mt], bfr[nt], acc[mt][nt], 0, 0, 0);
        __syncthreads();
    }

    for (int nt = 0; nt < 2; nt++) {
        int n = n0 + wc * 32 + nt * 16 + cl;
        float bv = bias[n];
        for (int mt = 0; mt < 4; mt++) {
            for (int r = 0; r < 4; r++) {
                int m = m0 + wr * 64 + mt * 16 + quad * 4 + r;
                float v = acc[mt][nt][r] + bv;
                if (f32) ((float*)C_)[(size_t)m * N + n] = v;
                else     ((short*)C_)[(size_t)m * N + n] = f2b(v);
            }
        }
    }
}

// ---------------------------------------------------------------------------
// Flash attention v15: v9 geometry (64 q-rows/block, 4 blocks/CU) with DMA
// staging. K dbuf (2x8KB), V single (8KB), Pp/P union (11KB) = 35.6KB LDS.
// 2 barriers/iter like v9, but staging latency hidden: K dbuf drained at
// barrier1 (staged one iter ahead); V drained at barrier2 (staged at top,
// consumed in PV after barrier2).
// ---------------------------------------------------------------------------
__global__ __launch_bounds__(256) void attn_kernel(
        const short* __restrict__ Q, const short* __restrict__ K,
        const short* __restrict__ VT, const short* __restrict__ rel,
        short* __restrict__ out) {
    const int tid = threadIdx.x;
    const int w = tid >> 6, lane = tid & 63, cl = lane & 15, quad = lane >> 4;
    const int bh = blockIdx.y, b = bh >> 4, h = bh & 15;
    const int I0 = blockIdx.x * 64;
    const int iw0 = I0 + w * 16;

    const short* Qp = Q + (size_t)bh * L_SEQ * DH;
    const short* Kp = K + (size_t)bh * L_SEQ * DH;
    const short* Vp = VT + (size_t)bh * DH * L_SEQ;

    __shared__ short Klds2[2][64 * 64];    // K dbuf, swizzled, 16KB
    __shared__ short Vtlds[64 * 64];       // V single, swizzled, 8KB
    __shared__ short Ulds[4][16 * 86];     // per-wave UNION: Pp then P, 11KB

    short* PpW = &Ulds[w][0];
    short* PW  = &Ulds[w][0];   // same storage; Pp fully consumed before P writes

    short8 aq[2];
    for (int c = 0; c < 2; c++)
        aq[c] = *(const short8*)(&Qp[(size_t)(iw0 + cl) * DH + c * 32 + quad * 8]);

    const float SCALE2 = 0.125f * 1.44269504088896340736f;  // /sqrt(64)*log2(e)
    const float FMAX = 32.0f;                               // fixed softmax shift

    // clamped-position row constants: q_i . E[0], q_i . E[1024]
    float addlo, addhi;
    {
        floatx4 Dc = {0.f, 0.f, 0.f, 0.f};
        int eidx = (cl == 1) ? 1024 : 0;
        for (int c = 0; c < 2; c++) {
            short8 ae = *(const short8*)(&rel[(size_t)eidx * DH + c * 32 + quad * 8]);
            Dc = __builtin_amdgcn_mfma_f32_16x16x32_bf16(ae, aq[c], Dc, 0, 0, 0);
        }
        float pcl = __shfl(Dc[0], cl, 64);
        float pch = __shfl(Dc[1], cl, 64);
        addlo = fmaf(pcl, SCALE2, -FMAX);
        addhi = fmaf(pch, SCALE2, -FMAX);
    }

    floatx4 O[4];
    for (int dt = 0; dt < 4; dt++) O[dt] = {0.f, 0.f, 0.f, 0.f};
    float lsum = 0.f;

    // DMA staging map (v13-proven): group g=w*2+s covers LDS rows g*8..g*8+7.
    // Lane l -> row r=g*8+(l>>3), slot p=l&7; source chunk c=p^(r&7).
    const int lr = lane >> 3;                    // 0..7
    const int lc8 = ((lane & 7) ^ lr) * 8;       // pre-swizzled col (shorts)

    // prologue: stage K tile 0 into Kbuf 0 (drained at first barrier)
    for (int s = 0; s < 2; s++) {
        int g = w * 2 + s;
        int r = g * 8 + lr;
        async_cp16(&Klds2[0][g * 512], &Kp[(size_t)r * DH + lc8]);
    }
    int cur = 0;

    for (int j0 = 0; j0 < L_SEQ; j0 += 64) {
        // barrier1: K[cur] DMA drained everywhere; all prev PV reads of V done
        __syncthreads();

        // stage V(current tile) into the single buffer (consumed after
        // barrier2), and K(next tile) into the other K buffer.
        for (int s = 0; s < 2; s++) {
            int g = w * 2 + s;
            int r = g * 8 + lr;
            async_cp16(&Vtlds[g * 512], &Vp[(size_t)r * L_SEQ + j0 + lc8]);
        }
        if (j0 + 64 < L_SEQ) {
            for (int s = 0; s < 2; s++) {
                int g = w * 2 + s;
                int r = g * 8 + lr;
                async_cp16(&Klds2[cur ^ 1][g * 512],
                           &Kp[(size_t)(j0 + 64 + r) * DH + lc8]);
            }
        }
        const short* Kb = &Klds2[cur][0];

        const bool hi_clamp = (j0 - iw0 - 15) >= 512;
        const bool lo_clamp = (j0 + 63 - iw0) <= -512;
        const bool banded = !(hi_clamp || lo_clamp);
        const float addc = hi_clamp ? addhi : addlo;

        // --- content: S^T[j_loc][i] = K Q^T ---
        floatx4 St[4];
        for (int jt = 0; jt < 4; jt++) {
            St[jt] = {0.f, 0.f, 0.f, 0.f};
            int row = jt * 16 + cl;
            for (int c = 0; c < 2; c++) {
                int pos = ((4 * c + quad) ^ (cl & 7)) * 8;
                short8 bk = *(const short8*)(&Kb[row * 64 + pos]);
                St[jt] = __builtin_amdgcn_mfma_f32_16x16x32_bf16(bk, aq[c], St[jt], 0, 0, 0);
            }
        }

        if (banded) {
            // Pp^T[t][i], t window 0..78
            floatx4 Pt[5];
            for (int pt = 0; pt < 5; pt++) Pt[pt] = {0.f, 0.f, 0.f, 0.f};
            const int base = j0 - iw0 - 15;
            for (int pt = 0; pt < 5; pt++) {
                int raw = pt * 16 + cl + base;
                int idx = (raw < -512 ? -512 : (raw > 512 ? 512 : raw)) + 512;
                const short* ep = rel + (size_t)idx * DH;
                for (int c = 0; c < 2; c++) {
                    short8 be = *(const short8*)(&ep[c * 32 + quad * 8]);
                    Pt[pt] = __builtin_amdgcn_mfma_f32_16x16x32_bf16(be, aq[c], Pt[pt], 0, 0, 0);
                }
            }
            // store transposed [i=cl][t], packed pairs (t even) — alias-safe
            for (int pt = 0; pt < 5; pt++) {
                int t = pt * 16 + quad * 4;
                st2(&PpW[cl * 86 + t],     pack2(Pt[pt][0], Pt[pt][1]));
                st2(&PpW[cl * 86 + t + 2], pack2(Pt[pt][2], Pt[pt][3]));
            }
            // wave-internal LDS RAW (memcpy stores may-alias -> ordered)
            for (int jt = 0; jt < 4; jt++)
                for (int r = 0; r < 4; r++) {
                    int t = jt * 16 + quad * 4 + r - cl + 15;   // 0..78
                    float pos = b2f(PpW[cl * 86 + t]);
                    St[jt][r] = fmaf(St[jt][r], SCALE2, fmaf(pos, SCALE2, -FMAX));
                }
        } else {
            for (int jt = 0; jt < 4; jt++)
                for (int r = 0; r < 4; r++)
                    St[jt][r] = fmaf(St[jt][r], SCALE2, addc);
        }

        // --- exp2 + sum ---
        for (int jt = 0; jt < 4; jt++)
            for (int r = 0; r < 4; r++) {
                float p = __builtin_amdgcn_exp2f(St[jt][r]);
                St[jt][r] = p;
                lsum += p;
            }

        // --- P -> per-wave LDS [i=cl][j_loc], swizzled (union: Pp is dead) ---
        for (int jt = 0; jt < 4; jt++)
            for (int pr = 0; pr < 2; pr++) {
                int jl = jt * 16 + quad * 4 + pr * 2;
                int addr = cl * 64 + ((jl >> 3) ^ (cl & 7)) * 8 + (jl & 7);
                st2(&PW[addr], pack2(St[jt][2 * pr], St[jt][2 * pr + 1]));
            }

        // barrier2: drains V DMA (conservative vmcnt(0) before s_barrier)
        __syncthreads();

        // --- O^T += V^T P^T ---
        for (int c = 0; c < 2; c++) {
            int ppos = ((4 * c + quad) ^ (cl & 7)) * 8;
            short8 bp = *(const short8*)(&PW[cl * 64 + ppos]);
            for (int dt = 0; dt < 4; dt++) {
                int row = dt * 16 + cl;
                int vpos = ((4 * c + quad) ^ (cl & 7)) * 8;
                short8 av = *(const short8*)(&Vtlds[row * 64 + vpos]);
                O[dt] = __builtin_amdgcn_mfma_f32_16x16x32_bf16(av, bp, O[dt], 0, 0, 0);
            }
        }
        cur ^= 1;
    }

    // --- l reduction (once) ---
    lsum += __shfl_xor(lsum, 16, 64);
    lsum += __shfl_xor(lsum, 32, 64);
    float inv = 1.0f / lsum;

    // --- epilogue: O^T*inv -> bf16 transpose via PW (reused, alias-safe) ---
    for (int dt = 0; dt < 4; dt++)
        for (int pr = 0; pr < 2; pr++) {
            int jl = dt * 16 + quad * 4 + pr * 2;   // d index
            int addr = cl * 64 + ((jl >> 3) ^ (cl & 7)) * 8 + (jl & 7);
            st2(&PW[addr], pack2(O[dt][2 * pr] * inv, O[dt][2 * pr + 1] * inv));
        }
    // wave-internal; memcpy stores ordered vs short8 reads
    size_t obase = ((size_t)b * L_SEQ + iw0 + cl) * D_MODEL + h * DH;
    for (int s = 0; s < 2; s++) {
        int c2 = quad * 2 + s;
        short8 o = *(const short8*)(&PW[cl * 64 + (c2 ^ (cl & 7)) * 8]);
        *(short8*)(&out[obase + c2 * 8]) = o;
    }
}

// ---------------------------------------------------------------------------
extern "C" void kernel_launch(void* const* d_in, const int* in_sizes, int n_in,
                              void* d_out, int out_size, void* d_ws, size_t ws_size,
                              hipStream_t stream) {
    const void* query = d_in[0];
    const void* key   = d_in[1];
    const void* value = d_in[2];
    const void* wq = d_in[3];  const void* bq = d_in[4];
    const void* wk = d_in[5];  const void* bk = d_in[6];
    const void* wv = d_in[7];  const void* bv = d_in[8];
    const void* wo = d_in[9];  const void* bo = d_in[10];
    const void* rel = d_in[11];

    // v4-proven 40.2MB layout.
    int* flag = (int*)d_ws;
    short* ws = (short*)d_ws + 16;                     // 32B offset
    const size_t WSZ = (size_t)D_MODEL * D_MODEL;      // 1M elems per weight
    const size_t TSZ = (size_t)MROWS * D_MODEL;        // 4M elems per tensor
    short* WT   = ws;                                  // 4 x WSZ (q,k,v,o)
    short* Qw   = ws + 4 * WSZ;
    short* Kw   = Qw + TSZ;
    short* Vtw  = Kw + TSZ;
    short* Attw = Vtw + TSZ;
    float* bias4 = (float*)(Attw + TSZ);               // 4096 fp32
    short* relb  = (short*)(bias4 + 4096);             // 65600 bf16

    // bf16-A scratch for the f32-input path (lifetimes verified, v12).
    short* Cq = (short*)d_out;
    short* Ck = (short*)d_out + TSZ;
    short* Cv = Attw;

    // Host-side dtype: in_sizes[0] is the query byte size. fp32 -> 16MB,
    // bf16 -> 8MB. Ambiguous value -> device fallback (detect_dtype).
    {
        long qb = (long)in_sizes[0];
        const long FP32B = (long)MROWS * D_MODEL * 4;
        const long BF16B = (long)MROWS * D_MODEL * 2;
        int fhost = (qb == FP32B) ? 1 : (qb == BF16B) ? 0 : -1;
        if (fhost >= 0)
            // memset byte-replicates: flag becomes 0 or 0x01010101; all
            // consumers use it as a boolean (f32 ? / if(f32)) -> safe.
            hipMemsetAsync(flag, fhost, 4, stream);
        else
            detect_dtype<<<1, 256, 0, stream>>>((const unsigned short*)query, flag);
    }

    norm_small<<<273, 256, 0, stream>>>(bq, bk, bv, bo, rel, bias4, relb, flag);
    transpose4<<<dim3(32, 32, 4), dim3(32, 8), 0, stream>>>(wq, wk, wv, wo, WT, flag);

    convert3<<<dim3(2048, 3), 256, 0, stream>>>(
        (const float*)query, (const float*)key, (const float*)value,
        Cq, Ck, Cv, flag);

    proj_gemm<<<dim3(8, 32, 3), 256, 0, stream>>>(query, key, value,
                                                  Cq, Ck, Cv, WT, bias4,
                                                  Qw, flag);

    attn_kernel<<<dim3(L_SEQ / 64, BH), 256, 0, stream>>>(Qw, Kw, Vtw, relb, Attw);

    out_gemm<<<dim3(16, 32), 256, 0, stream>>>(Attw, WT + 3 * WSZ, bias4 + 3072,
                                               d_out, flag);
}

// Round 8
// 377.063 us; speedup vs baseline: 1.1018x; 1.0294x over previous
//
#include <hip/hip_runtime.h>
#include <hip/hip_bf16.h>

// ---------------------------------------------------------------------------
// RelativeMultiHeadAttention: B=2, L=2048, D=1024, H=16, d=64, MAX_REL=512
// Inputs fp32 (auto-detected vs bf16). Internals bf16 MFMA + fp32 accum.
//
// v16 = v12 (best total 382.1us; attn reg-staging 141.7us) + T1 XCD-chunked
// blockIdx swizzle on attn/proj/out + host-side dtype flag (v15-validated).
//   Rationale: attn FETCH=197MB vs 24MB unique -> 8x HBM overfetch from
//   XCD round-robin (32 blocks sharing one bh's K/V spread over 8 L2s).
//   Swizzle gives each XCD 4 consecutive bh (3MB < 4MB L2). proj/out have
//   the same geometry bug on A-panels (full A per XCD); chunked swizzle
//   gives full-B x 4-A-panel chunks (3MB/XCD).
//   DMA-staging lever retired: v13 173.9 / v14 172.2 / v15 147.5 all lost
//   to v9's 141.7 reg staging. attn body below is byte-identical to v12
//   except the block-id swizzle.
// ---------------------------------------------------------------------------

typedef __attribute__((ext_vector_type(8))) short short8;   // 8 x bf16 frag
typedef __attribute__((ext_vector_type(4))) float floatx4;

#define L_SEQ 2048
#define D_MODEL 1024
#define NHEAD 16
#define DH 64
#define BH 32           // B*H
#define MROWS 4096      // B*L

__device__ inline float b2f(short s) {
    unsigned int u = ((unsigned int)(unsigned short)s) << 16;
    float f; __builtin_memcpy(&f, &u, 4); return f;
}
__device__ inline short f2b(float f) {
    unsigned int u; __builtin_memcpy(&u, &f, 4);
    u += 0x7fffu + ((u >> 16) & 1u);   // round-to-nearest-even
    return (short)(u >> 16);
}
// packed f32x2 -> bf16x2 (v_cvt_pk_bf16_f32 on gfx950)
__device__ inline unsigned int pack2(float a, float b) {
    __hip_bfloat162 h = __float22bfloat162_rn(make_float2(a, b));
    unsigned int u; __builtin_memcpy(&u, &h, 4); return u;
}
// alias-safe 4B store into a short-typed LDS array (ds_write_b32)
__device__ inline void st2(short* p, unsigned int v) {
    __builtin_memcpy(p, &v, 4);
}
// async global->LDS, 16B per lane; lds base must be wave-uniform
__device__ inline void async_cp16(short* lds, const short* g) {
    __builtin_amdgcn_global_load_lds(
        (const __attribute__((address_space(1))) unsigned int*)g,
        (__attribute__((address_space(3))) unsigned int*)lds, 16, 0, 0);
}

// ---------------------------------------------------------------------------
// dtype detector (FALLBACK ONLY): bf16 inf/nan patterns in first 64K shorts.
// ---------------------------------------------------------------------------
__global__ __launch_bounds__(256) void detect_dtype(
        const unsigned short* __restrict__ q, int* __restrict__ flag) {
    __shared__ int s[256];
    int tid = threadIdx.x, cnt = 0;
    for (int i = tid; i < 65536; i += 256)
        if ((q[i] & 0x7F80u) == 0x7F80u) cnt++;
    s[tid] = cnt; __syncthreads();
    for (int st = 128; st; st >>= 1) {
        if (tid < st) s[tid] += s[tid + st];
        __syncthreads();
    }
    if (tid == 0) *flag = (s[0] > 4) ? 1 : 0;   // 1 = inputs are fp32
}

// ---------------------------------------------------------------------------
// Canonicalize small tensors: 4 biases -> fp32[4096], rel_emb -> bf16[65600]
// ---------------------------------------------------------------------------
__global__ __launch_bounds__(256) void norm_small(
        const void* __restrict__ bq, const void* __restrict__ bk,
        const void* __restrict__ bv, const void* __restrict__ bo,
        const void* __restrict__ rel, float* __restrict__ bias4,
        short* __restrict__ relb, const int* __restrict__ flagp) {
    const int f32 = *flagp;
    int t = blockIdx.x * 256 + threadIdx.x;
    if (t < 4096) {
        const void* src = (t < 1024) ? bq : (t < 2048) ? bk : (t < 3072) ? bv : bo;
        int i = t & 1023;
        bias4[t] = f32 ? ((const float*)src)[i] : b2f(((const short*)src)[i]);
    } else if (t < 4096 + 65600) {
        int i = t - 4096;
        relb[i] = f32 ? f2b(((const float*)rel)[i]) : ((const short*)rel)[i];
    }
}

// ---------------------------------------------------------------------------
// Weight transpose: 4 x (1024,1024) (c,n) -> bf16 (n,c)
// ---------------------------------------------------------------------------
__global__ __launch_bounds__(256) void transpose4(
        const void* __restrict__ w0, const void* __restrict__ w1,
        const void* __restrict__ w2, const void* __restrict__ w3,
        short* __restrict__ dst, const int* __restrict__ flagp) {
    const int f32 = *flagp;
    __shared__ short tile[32][33];
    const void* src = (blockIdx.z == 0) ? w0 : (blockIdx.z == 1) ? w1
                    : (blockIdx.z == 2) ? w2 : w3;
    short* d = dst + (size_t)blockIdx.z * (D_MODEL * D_MODEL);
    int x = blockIdx.x * 32 + threadIdx.x;   // n
    int y0 = blockIdx.y * 32;                // c base
    for (int yy = threadIdx.y; yy < 32; yy += 8) {
        size_t idx = (size_t)(y0 + yy) * D_MODEL + x;
        tile[yy][threadIdx.x] = f32 ? f2b(((const float*)src)[idx])
                                    : ((const short*)src)[idx];
    }
    __syncthreads();
    int x0 = blockIdx.x * 32;
    for (int yy = threadIdx.y; yy < 32; yy += 8)
        d[(size_t)(x0 + yy) * D_MODEL + y0 + threadIdx.x] = tile[threadIdx.x][yy];
}

// ---------------------------------------------------------------------------
// convert3: fp32 Q/K/V inputs -> canonical bf16 (memory-bound, ~15us).
// ---------------------------------------------------------------------------
__global__ __launch_bounds__(256) void convert3(
        const float* __restrict__ q, const float* __restrict__ k,
        const float* __restrict__ v, short* __restrict__ abf_q,
        short* __restrict__ abf_k, short* __restrict__ abf_v,
        const int* __restrict__ flagp) {
    if (!*flagp) return;
    const int z = blockIdx.y;
    const float* src = (z == 0) ? q : (z == 1) ? k : v;
    short* dst = (z == 0) ? abf_q : (z == 1) ? abf_k : abf_v;
    size_t i8 = ((size_t)blockIdx.x * 256 + threadIdx.x) * 8;
    float4 f0 = *(const float4*)(&src[i8]);
    float4 f1 = *(const float4*)(&src[i8 + 4]);
    uint4 s;
    s.x = pack2(f0.x, f0.y); s.y = pack2(f0.z, f0.w);
    s.z = pack2(f1.x, f1.y); s.w = pack2(f1.z, f1.w);
    *(uint4*)(&dst[i8]) = s;
}

// ---------------------------------------------------------------------------
// Fused QKV projection GEMM: z = 0,1,2.  C = A(4096,1024) @ WT^T + bias.
// A and B both bf16 -> global_load_lds width 16 (m97 layout, stride-32 rows).
// XCD swizzle: chunk = full-B(8 n-tiles) x 4 m-panels = 3MB per XCD L2.
// z 0/1 -> (b,h,l,d) bf16; z=2 -> (b,h,d,l) bf16 (V^T).
// ---------------------------------------------------------------------------
__global__ __launch_bounds__(256) void proj_gemm(
        const void* __restrict__ Aq, const void* __restrict__ Ak,
        const void* __restrict__ Av, const short* __restrict__ Cq,
        const short* __restrict__ Ck, const short* __restrict__ Cv,
        const short* __restrict__ WT, const float* __restrict__ bias4,
        short* __restrict__ Qout, const int* __restrict__ flagp) {
    const int f32 = *flagp;
    const int z = blockIdx.z;
    // A source: converted bf16 scratch when inputs were fp32, else originals
    const short* A_ = f32 ? ((z == 0) ? Cq : (z == 1) ? Ck : Cv)
                          : (const short*)((z == 0) ? Aq : (z == 1) ? Ak : Av);
    const short* BT = WT + (size_t)z * (D_MODEL * D_MODEL);
    const float* bias = bias4 + z * 1024;
    short* C = Qout + (size_t)z * ((size_t)MROWS * D_MODEL);
    const int K = D_MODEL;

    __shared__ short Alds[128 * 32];
    __shared__ short Blds[128 * 32];
    const int tid = threadIdx.x;
    const int w = tid >> 6, lane = tid & 63, cl = lane & 15, quad = lane >> 4;
    const int wr = w >> 1, wc = w & 1;
    // T1 XCD-chunked bijective swizzle within the 256-block z-plane
    // (hw XCD ~ linear%8; 256%8==0). XCD k -> bx all 8, by in [4k,4k+4).
    int wg = blockIdx.x + 8 * blockIdx.y;
    wg = (wg & 7) * 32 + (wg >> 3);
    const int m0 = (wg >> 3) * 128, n0 = (wg & 7) * 128;
    const int grow = lane >> 2, gcol = (lane & 3) * 8;   // async staging map

    floatx4 acc[4][4];
    for (int i = 0; i < 4; i++)
        for (int j = 0; j < 4; j++)
            acc[i][j] = {0.f, 0.f, 0.f, 0.f};

    for (int k0 = 0; k0 < K; k0 += 32) {
        // A and B: async direct-to-LDS (wave-uniform base + lane*16B)
        for (int s = 0; s < 2; s++) {
            int r = w * 32 + s * 16;
            async_cp16(&Blds[r * 32], &BT[(size_t)(n0 + r + grow) * K + k0 + gcol]);
            async_cp16(&Alds[r * 32], &A_[(size_t)(m0 + r + grow) * K + k0 + gcol]);
        }
        __syncthreads();

        short8 af[4], bfr[4];
        for (int mt = 0; mt < 4; mt++)
            af[mt] = *(const short8*)(&Alds[(wr * 64 + mt * 16 + cl) * 32 + quad * 8]);
        for (int nt = 0; nt < 4; nt++)
            bfr[nt] = *(const short8*)(&Blds[(wc * 64 + nt * 16 + cl) * 32 + quad * 8]);
        for (int mt = 0; mt < 4; mt++)
            for (int nt = 0; nt < 4; nt++)
                acc[mt][nt] = __builtin_amdgcn_mfma_f32_16x16x32_bf16(
                    af[mt], bfr[nt], acc[mt][nt], 0, 0, 0);
        __syncthreads();
    }

    for (int nt = 0; nt < 4; nt++) {
        int n = n0 + wc * 64 + nt * 16 + cl;
        float bv = bias[n];
        int h = n >> 6, d = n & 63;
        for (int mt = 0; mt < 4; mt++) {
            for (int r = 0; r < 4; r++) {
                int m = m0 + wr * 64 + mt * 16 + quad * 4 + r;
                float v = acc[mt][nt][r] + bv;
                int b = m >> 11, i = m & 2047;
                if (z < 2)
                    C[(((size_t)(b * NHEAD + h)) * L_SEQ + i) * DH + d] = f2b(v);
                else
                    C[(((size_t)(b * NHEAD + h)) * DH + d) * L_SEQ + i] = f2b(v);
            }
        }
    }
}

// ---------------------------------------------------------------------------
// Output GEMM: C(4096,1024) = A @ WT^T + bias.  128x64 tile, full async.
// XCD swizzle: chunk = full-B(16 n-tiles) x 4 m-panels = 3MB per XCD L2.
// ---------------------------------------------------------------------------
__global__ __launch_bounds__(256) void out_gemm(
        const short* __restrict__ A, const short* __restrict__ BT,
        const float* __restrict__ bias, void* __restrict__ C_,
        const int* __restrict__ flagp) {
    const int f32 = *flagp;
    const int K = D_MODEL, N = D_MODEL;
    __shared__ short Alds[128 * 32];
    __shared__ short Blds[64 * 32];
    const int tid = threadIdx.x;
    const int w = tid >> 6, lane = tid & 63, cl = lane & 15, quad = lane >> 4;
    const int wr = w >> 1, wc = w & 1;
    // T1 XCD-chunked bijective swizzle (512 blocks; 512%8==0)
    int wg = blockIdx.x + 16 * blockIdx.y;
    wg = (wg & 7) * 64 + (wg >> 3);
    const int m0 = (wg >> 4) * 128, n0 = (wg & 15) * 64;
    const int grow = lane >> 2, gcol = (lane & 3) * 8;

    floatx4 acc[4][2];
    for (int i = 0; i < 4; i++)
        for (int j = 0; j < 2; j++)
            acc[i][j] = {0.f, 0.f, 0.f, 0.f};

    for (int k0 = 0; k0 < K; k0 += 32) {
        for (int s = 0; s < 2; s++) {
            int r = w * 32 + s * 16;
            async_cp16(&Alds[r * 32], &A[(size_t)(m0 + r + grow) * K + k0 + gcol]);
        }
        {
            int r = w * 16;
            async_cp16(&Blds[r * 32], &BT[(size_t)(n0 + r + grow) * K + k0 + gcol]);
        }
        __syncthreads();

        short8 af[4], bfr[2];
        for (int mt = 0; mt < 4; mt++)
            af[mt] = *(const short8*)(&Alds[(wr * 64 + mt * 16 + cl) * 32 + quad * 8]);
        for (int nt = 0; nt < 2; nt++)
            bfr[nt] = *(const short8*)(&Blds[(wc * 32 + nt * 16 + cl) * 32 + quad * 8]);
        for (int mt = 0; mt < 4; mt++)
            for (int nt = 0; nt < 2; nt++)
                acc[mt][nt] = __builtin_amdgcn_mfma_f32_16x16x32_bf16(
                    af[mt], bfr[nt], acc[mt][nt], 0, 0, 0);
        __syncthreads();
    }

    for (int nt = 0; nt < 2; nt++) {
        int n = n0 + wc * 32 + nt * 16 + cl;
        float bv = bias[n];
        for (int mt = 0; mt < 4; mt++) {
            for (int r = 0; r < 4; r++) {
                int m = m0 + wr * 64 + mt * 16 + quad * 4 + r;
                float v = acc[mt][nt][r] + bv;
                if (f32) ((float*)C_)[(size_t)m * N + n] = v;
                else     ((short*)C_)[(size_t)m * N + n] = f2b(v);
            }
        }
    }
}

// ---------------------------------------------------------------------------
// Flash attention (v9/v12 body + XCD swizzle): transposed scores +
// fixed-shift softmax + banded pos. TBAA-safe LDS stores. 34.4 KB LDS.
// Swizzle: XCD k owns bh in [4k,4k+4) -> K/V/Q working set 3MB < 4MB L2.
// ---------------------------------------------------------------------------
__global__ __launch_bounds__(256) void attn_kernel(
        const short* __restrict__ Q, const short* __restrict__ K,
        const short* __restrict__ VT, const short* __restrict__ rel,
        short* __restrict__ out) {
    const int tid = threadIdx.x;
    const int w = tid >> 6, lane = tid & 63, cl = lane & 15, quad = lane >> 4;
    // T1 XCD-chunked bijective swizzle (1024 blocks; 1024%8==0):
    // hw linear = x + 32*y; XCD ~ linear%8 -> chunk of 128 = 4 bh.
    int wg = blockIdx.x + 32 * blockIdx.y;
    wg = (wg & 7) * 128 + (wg >> 3);
    const int bh = wg >> 5, b = bh >> 4, h = bh & 15;
    const int I0 = (wg & 31) * 64;
    const int iw0 = I0 + w * 16;

    const short* Qp = Q + (size_t)bh * L_SEQ * DH;
    const short* Kp = K + (size_t)bh * L_SEQ * DH;
    const short* Vp = VT + (size_t)bh * DH * L_SEQ;

    __shared__ short Klds[64 * 64];        // swizzled, 8KB
    __shared__ short Vtlds[64 * 64];       // swizzled, 8KB
    __shared__ short PpLds[4][16 * 86];    // per-wave pos [i][t], bf16, 10.75KB
    __shared__ short Plds[4][16 * 64];     // per-wave P, swizzled, 8KB

    short* PpW = &PpLds[w][0];
    short* PW  = &Plds[w][0];

    short8 aq[2];
    for (int c = 0; c < 2; c++)
        aq[c] = *(const short8*)(&Qp[(size_t)(iw0 + cl) * DH + c * 32 + quad * 8]);

    const float SCALE2 = 0.125f * 1.44269504088896340736f;  // /sqrt(64)*log2(e)
    const float FMAX = 32.0f;                               // fixed softmax shift

    // clamped-position row constants: q_i . E[0], q_i . E[1024]
    float addlo, addhi;
    {
        floatx4 Dc = {0.f, 0.f, 0.f, 0.f};
        int eidx = (cl == 1) ? 1024 : 0;
        for (int c = 0; c < 2; c++) {
            short8 ae = *(const short8*)(&rel[(size_t)eidx * DH + c * 32 + quad * 8]);
            Dc = __builtin_amdgcn_mfma_f32_16x16x32_bf16(ae, aq[c], Dc, 0, 0, 0);
        }
        float pcl = __shfl(Dc[0], cl, 64);
        float pch = __shfl(Dc[1], cl, 64);
        addlo = fmaf(pcl, SCALE2, -FMAX);
        addhi = fmaf(pch, SCALE2, -FMAX);
    }

    floatx4 O[4];
    for (int dt = 0; dt < 4; dt++) O[dt] = {0.f, 0.f, 0.f, 0.f};
    float lsum = 0.f;

    const int srow = tid >> 2;
    const int spair = (tid & 3) * 2;

    for (int j0 = 0; j0 < L_SEQ; j0 += 64) {
        for (int s = 0; s < 2; s++) {
            int chunk = spair + s;
            int pos = chunk ^ (srow & 7);
            *(short8*)(&Klds[srow * 64 + pos * 8]) =
                *(const short8*)(&Kp[(size_t)(j0 + srow) * DH + chunk * 8]);
            *(short8*)(&Vtlds[srow * 64 + pos * 8]) =
                *(const short8*)(&Vp[(size_t)srow * L_SEQ + j0 + chunk * 8]);
        }
        __syncthreads();

        const bool hi_clamp = (j0 - iw0 - 15) >= 512;
        const bool lo_clamp = (j0 + 63 - iw0) <= -512;
        const bool banded = !(hi_clamp || lo_clamp);
        const float addc = hi_clamp ? addhi : addlo;

        // --- content: S^T[j_loc][i] = K Q^T ---
        floatx4 St[4];
        for (int jt = 0; jt < 4; jt++) {
            St[jt] = {0.f, 0.f, 0.f, 0.f};
            int row = jt * 16 + cl;
            for (int c = 0; c < 2; c++) {
                int pos = ((4 * c + quad) ^ (cl & 7)) * 8;
                short8 bk = *(const short8*)(&Klds[row * 64 + pos]);
                St[jt] = __builtin_amdgcn_mfma_f32_16x16x32_bf16(bk, aq[c], St[jt], 0, 0, 0);
            }
        }

        if (banded) {
            // Pp^T[t][i], t window 0..78
            floatx4 Pt[5];
            for (int pt = 0; pt < 5; pt++) Pt[pt] = {0.f, 0.f, 0.f, 0.f};
            const int base = j0 - iw0 - 15;
            for (int pt = 0; pt < 5; pt++) {
                int raw = pt * 16 + cl + base;
                int idx = (raw < -512 ? -512 : (raw > 512 ? 512 : raw)) + 512;
                const short* ep = rel + (size_t)idx * DH;
                for (int c = 0; c < 2; c++) {
                    short8 be = *(const short8*)(&ep[c * 32 + quad * 8]);
                    Pt[pt] = __builtin_amdgcn_mfma_f32_16x16x32_bf16(be, aq[c], Pt[pt], 0, 0, 0);
                }
            }
            // store transposed [i=cl][t], packed pairs (t even) — alias-safe
            for (int pt = 0; pt < 5; pt++) {
                int t = pt * 16 + quad * 4;
                st2(&PpW[cl * 86 + t],     pack2(Pt[pt][0], Pt[pt][1]));
                st2(&PpW[cl * 86 + t + 2], pack2(Pt[pt][2], Pt[pt][3]));
            }
            // wave-internal LDS RAW (memcpy stores may-alias -> ordered)
            for (int jt = 0; jt < 4; jt++)
                for (int r = 0; r < 4; r++) {
                    int t = jt * 16 + quad * 4 + r - cl + 15;   // 0..78
                    float pos = b2f(PpW[cl * 86 + t]);
                    St[jt][r] = fmaf(St[jt][r], SCALE2, fmaf(pos, SCALE2, -FMAX));
                }
        } else {
            for (int jt = 0; jt < 4; jt++)
                for (int r = 0; r < 4; r++)
                    St[jt][r] = fmaf(St[jt][r], SCALE2, addc);
        }

        // --- exp2 + sum ---
        for (int jt = 0; jt < 4; jt++)
            for (int r = 0; r < 4; r++) {
                float p = __builtin_amdgcn_exp2f(St[jt][r]);
                St[jt][r] = p;
                lsum += p;
            }

        // --- P -> per-wave LDS [i=cl][j_loc], swizzled, alias-safe b32 ---
        for (int jt = 0; jt < 4; jt++)
            for (int pr = 0; pr < 2; pr++) {
                int jl = jt * 16 + quad * 4 + pr * 2;
                int addr = cl * 64 + ((jl >> 3) ^ (cl & 7)) * 8 + (jl & 7);
                st2(&PW[addr], pack2(St[jt][2 * pr], St[jt][2 * pr + 1]));
            }

        // --- O^T += V^T P^T ---
        for (int c = 0; c < 2; c++) {
            int ppos = ((4 * c + quad) ^ (cl & 7)) * 8;
            short8 bp = *(const short8*)(&PW[cl * 64 + ppos]);
            for (int dt = 0; dt < 4; dt++) {
                int row = dt * 16 + cl;
                int vpos = ((4 * c + quad) ^ (cl & 7)) * 8;
                short8 av = *(const short8*)(&Vtlds[row * 64 + vpos]);
                O[dt] = __builtin_amdgcn_mfma_f32_16x16x32_bf16(av, bp, O[dt], 0, 0, 0);
            }
        }
        __syncthreads();   // before next staging overwrites K/V tiles
    }

    // --- l reduction (once) ---
    lsum += __shfl_xor(lsum, 16, 64);
    lsum += __shfl_xor(lsum, 32, 64);
    float inv = 1.0f / lsum;

    // --- epilogue: O^T*inv -> bf16 transpose via PW (reused, alias-safe) ---
    for (int dt = 0; dt < 4; dt++)
        for (int pr = 0; pr < 2; pr++) {
            int jl = dt * 16 + quad * 4 + pr * 2;   // d index
            int addr = cl * 64 + ((jl >> 3) ^ (cl & 7)) * 8 + (jl & 7);
            st2(&PW[addr], pack2(O[dt][2 * pr] * inv, O[dt][2 * pr + 1] * inv));
        }
    // wave-internal; memcpy stores ordered vs short8 reads
    size_t obase = ((size_t)b * L_SEQ + iw0 + cl) * D_MODEL + h * DH;
    for (int s = 0; s < 2; s++) {
        int c2 = quad * 2 + s;
        short8 o = *(const short8*)(&PW[cl * 64 + (c2 ^ (cl & 7)) * 8]);
        *(short8*)(&out[obase + c2 * 8]) = o;
    }
}

// ---------------------------------------------------------------------------
extern "C" void kernel_launch(void* const* d_in, const int* in_sizes, int n_in,
                              void* d_out, int out_size, void* d_ws, size_t ws_size,
                              hipStream_t stream) {
    const void* query = d_in[0];
    const void* key   = d_in[1];
    const void* value = d_in[2];
    const void* wq = d_in[3];  const void* bq = d_in[4];
    const void* wk = d_in[5];  const void* bk = d_in[6];
    const void* wv = d_in[7];  const void* bv = d_in[8];
    const void* wo = d_in[9];  const void* bo = d_in[10];
    const void* rel = d_in[11];

    // v4-proven 40.2MB layout.
    int* flag = (int*)d_ws;
    short* ws = (short*)d_ws + 16;                     // 32B offset
    const size_t WSZ = (size_t)D_MODEL * D_MODEL;      // 1M elems per weight
    const size_t TSZ = (size_t)MROWS * D_MODEL;        // 4M elems per tensor
    short* WT   = ws;                                  // 4 x WSZ (q,k,v,o)
    short* Qw   = ws + 4 * WSZ;
    short* Kw   = Qw + TSZ;
    short* Vtw  = Kw + TSZ;
    short* Attw = Vtw + TSZ;
    float* bias4 = (float*)(Attw + TSZ);               // 4096 fp32
    short* relb  = (short*)(bias4 + 4096);             // 65600 bf16

    // bf16-A scratch for the f32-input path (lifetimes verified, v12).
    short* Cq = (short*)d_out;
    short* Ck = (short*)d_out + TSZ;
    short* Cv = Attw;

    // Host-side dtype: in_sizes[0] is the query byte size. fp32 -> 16MB,
    // bf16 -> 8MB. Ambiguous value -> device fallback (detect_dtype).
    {
        long qb = (long)in_sizes[0];
        const long FP32B = (long)MROWS * D_MODEL * 4;
        const long BF16B = (long)MROWS * D_MODEL * 2;
        int fhost = (qb == FP32B) ? 1 : (qb == BF16B) ? 0 : -1;
        if (fhost >= 0)
            hipMemsetAsync(flag, fhost, 4, stream);   // 0 or 0x01010101: bool-safe
        else
            detect_dtype<<<1, 256, 0, stream>>>((const unsigned short*)query, flag);
    }

    norm_small<<<273, 256, 0, stream>>>(bq, bk, bv, bo, rel, bias4, relb, flag);
    transpose4<<<dim3(32, 32, 4), dim3(32, 8), 0, stream>>>(wq, wk, wv, wo, WT, flag);

    convert3<<<dim3(2048, 3), 256, 0, stream>>>(
        (const float*)query, (const float*)key, (const float*)value,
        Cq, Ck, Cv, flag);

    proj_gemm<<<dim3(8, 32, 3), 256, 0, stream>>>(query, key, value,
                                                  Cq, Ck, Cv, WT, bias4,
                                                  Qw, flag);

    attn_kernel<<<dim3(L_SEQ / 64, BH), 256, 0, stream>>>(Qw, Kw, Vtw, relb, Attw);

    out_gemm<<<dim3(16, 32), 256, 0, stream>>>(Attw, WT + 3 * WSZ, bias4 + 3072,
                                               d_out, flag);
}

// Round 9
// 375.008 us; speedup vs baseline: 1.1078x; 1.0055x over previous
//
#include <hip/hip_runtime.h>
#include <hip/hip_bf16.h>

// ---------------------------------------------------------------------------
// RelativeMultiHeadAttention: B=2, L=2048, D=1024, H=16, d=64, MAX_REL=512
// Inputs fp32 (auto-detected vs bf16). Internals bf16 MFMA + fp32 accum.
//
// v17 = v16 (best 377.1us; attn 138.5, FETCH fixed by XCD swizzle) +
//   (a) attn Pp path de-scalarized: position scores stored as f32 via
//       ds_write_b128 (pad-92 rows, bank-checked), read via aligned
//       ds_read_b32. Removes 10 pack2 + 16 b2f + 16 scalar u16 reads per
//       banded iter. P stores merged into ds_write_b64 pairs. Pp/P LDS
//       union (sequential use) -> 39.9KB total, 4 blocks/CU kept. All
//       union accesses memcpy-based (TBAA lesson of v5-v7).
//   (b) norm_small + transpose4 + convert3 fused into one prep_all launch
//       (role by block-id range; same 256-thread blocks) -> -2 launches.
// GEMMs byte-identical to v16.
// History: v9 141.7 / v13-15 staging-family all slower / v16 138.5 attn.
// ---------------------------------------------------------------------------

typedef __attribute__((ext_vector_type(8))) short short8;   // 8 x bf16 frag
typedef __attribute__((ext_vector_type(4))) float floatx4;

#define L_SEQ 2048
#define D_MODEL 1024
#define NHEAD 16
#define DH 64
#define BH 32           // B*H
#define MROWS 4096      // B*L
#define PPAD 92         // Pp row pad (f32): %4==0 (b128 align), 23*cl distinct banks

__device__ inline float b2f(short s) {
    unsigned int u = ((unsigned int)(unsigned short)s) << 16;
    float f; __builtin_memcpy(&f, &u, 4); return f;
}
__device__ inline short f2b(float f) {
    unsigned int u; __builtin_memcpy(&u, &f, 4);
    u += 0x7fffu + ((u >> 16) & 1u);   // round-to-nearest-even
    return (short)(u >> 16);
}
// packed f32x2 -> bf16x2 (v_cvt_pk_bf16_f32 on gfx950)
__device__ inline unsigned int pack2(float a, float b) {
    __hip_bfloat162 h = __float22bfloat162_rn(make_float2(a, b));
    unsigned int u; __builtin_memcpy(&u, &h, 4); return u;
}
// alias-safe 4B store into a short-typed LDS array (ds_write_b32)
__device__ inline void st2(short* p, unsigned int v) {
    __builtin_memcpy(p, &v, 4);
}
// alias-safe 8B store (ds_write_b64): two packed bf16x2 words
__device__ inline void st4(short* p, unsigned int a, unsigned int b) {
    unsigned int v[2] = {a, b}; __builtin_memcpy(p, v, 8);
}
// alias-safe 16B f32x4 store (ds_write_b128)
__device__ inline void stf4(short* p, floatx4 v) {
    __builtin_memcpy(p, &v, 16);
}
// alias-safe f32 load (ds_read_b32)
__device__ inline float ldf(const short* p) {
    float f; __builtin_memcpy(&f, p, 4); return f;
}
// async global->LDS, 16B per lane; lds base must be wave-uniform
__device__ inline void async_cp16(short* lds, const short* g) {
    __builtin_amdgcn_global_load_lds(
        (const __attribute__((address_space(1))) unsigned int*)g,
        (__attribute__((address_space(3))) unsigned int*)lds, 16, 0, 0);
}

// ---------------------------------------------------------------------------
// dtype detector (FALLBACK ONLY): bf16 inf/nan patterns in first 64K shorts.
// ---------------------------------------------------------------------------
__global__ __launch_bounds__(256) void detect_dtype(
        const unsigned short* __restrict__ q, int* __restrict__ flag) {
    __shared__ int s[256];
    int tid = threadIdx.x, cnt = 0;
    for (int i = tid; i < 65536; i += 256)
        if ((q[i] & 0x7F80u) == 0x7F80u) cnt++;
    s[tid] = cnt; __syncthreads();
    for (int st = 128; st; st >>= 1) {
        if (tid < st) s[tid] += s[tid + st];
        __syncthreads();
    }
    if (tid == 0) *flag = (s[0] > 4) ? 1 : 0;   // 1 = inputs are fp32
}

// ---------------------------------------------------------------------------
// prep_all: fused norm_small + transpose4 + convert3 (one launch).
// Roles by block id: [0,4096) transpose, [4096,10240) convert, [10240,10513) norm.
// ---------------------------------------------------------------------------
__global__ __launch_bounds__(256) void prep_all(
        const void* __restrict__ w0, const void* __restrict__ w1,
        const void* __restrict__ w2, const void* __restrict__ w3,
        const void* __restrict__ bq, const void* __restrict__ bk,
        const void* __restrict__ bv, const void* __restrict__ bo,
        const void* __restrict__ rel,
        const float* __restrict__ q, const float* __restrict__ k,
        const float* __restrict__ v,
        short* __restrict__ WT, float* __restrict__ bias4,
        short* __restrict__ relb,
        short* __restrict__ Cq, short* __restrict__ Ck, short* __restrict__ Cv,
        const int* __restrict__ flagp) {
    const int f32 = *flagp;
    const int id = blockIdx.x;
    const int tid = threadIdx.x;

    if (id < 4096) {
        // ---- weight transpose role: 1024 blocks per weight ----
        __shared__ short tile[32][33];
        const int wz = id >> 10, rem = id & 1023;
        const int bx = rem & 31, by = rem >> 5;
        const int tx = tid & 31, ty = tid >> 5;   // (32,8)
        const void* src = (wz == 0) ? w0 : (wz == 1) ? w1 : (wz == 2) ? w2 : w3;
        short* d = WT + (size_t)wz * (D_MODEL * D_MODEL);
        int x = bx * 32 + tx;
        int y0 = by * 32;
        for (int yy = ty; yy < 32; yy += 8) {
            size_t idx = (size_t)(y0 + yy) * D_MODEL + x;
            tile[yy][tx] = f32 ? f2b(((const float*)src)[idx])
                               : ((const short*)src)[idx];
        }
        __syncthreads();
        int x0 = bx * 32;
        for (int yy = ty; yy < 32; yy += 8)
            d[(size_t)(x0 + yy) * D_MODEL + y0 + tx] = tile[tx][yy];
    } else if (id < 10240) {
        // ---- fp32->bf16 convert role: 2048 blocks per tensor ----
        if (!f32) return;
        const int cid = id - 4096;
        const int z = cid >> 11;            // 0..2
        const int bx = cid & 2047;
        const float* src = (z == 0) ? q : (z == 1) ? k : v;
        short* dst = (z == 0) ? Cq : (z == 1) ? Ck : Cv;
        size_t i8 = ((size_t)bx * 256 + tid) * 8;
        float4 f0 = *(const float4*)(&src[i8]);
        float4 f1 = *(const float4*)(&src[i8 + 4]);
        uint4 s;
        s.x = pack2(f0.x, f0.y); s.y = pack2(f0.z, f0.w);
        s.z = pack2(f1.x, f1.y); s.w = pack2(f1.z, f1.w);
        *(uint4*)(&dst[i8]) = s;
    } else {
        // ---- small-tensor canonicalize role: 273 blocks ----
        int t = (id - 10240) * 256 + tid;
        if (t < 4096) {
            const void* src = (t < 1024) ? bq : (t < 2048) ? bk
                            : (t < 3072) ? bv : bo;
            int i = t & 1023;
            bias4[t] = f32 ? ((const float*)src)[i] : b2f(((const short*)src)[i]);
        } else if (t < 4096 + 65600) {
            int i = t - 4096;
            relb[i] = f32 ? f2b(((const float*)rel)[i]) : ((const short*)rel)[i];
        }
    }
}

// ---------------------------------------------------------------------------
// Fused QKV projection GEMM (v16, unchanged): z = 0,1,2.
// ---------------------------------------------------------------------------
__global__ __launch_bounds__(256) void proj_gemm(
        const void* __restrict__ Aq, const void* __restrict__ Ak,
        const void* __restrict__ Av, const short* __restrict__ Cq,
        const short* __restrict__ Ck, const short* __restrict__ Cv,
        const short* __restrict__ WT, const float* __restrict__ bias4,
        short* __restrict__ Qout, const int* __restrict__ flagp) {
    const int f32 = *flagp;
    const int z = blockIdx.z;
    const short* A_ = f32 ? ((z == 0) ? Cq : (z == 1) ? Ck : Cv)
                          : (const short*)((z == 0) ? Aq : (z == 1) ? Ak : Av);
    const short* BT = WT + (size_t)z * (D_MODEL * D_MODEL);
    const float* bias = bias4 + z * 1024;
    short* C = Qout + (size_t)z * ((size_t)MROWS * D_MODEL);
    const int K = D_MODEL;

    __shared__ short Alds[128 * 32];
    __shared__ short Blds[128 * 32];
    const int tid = threadIdx.x;
    const int w = tid >> 6, lane = tid & 63, cl = lane & 15, quad = lane >> 4;
    const int wr = w >> 1, wc = w & 1;
    int wg = blockIdx.x + 8 * blockIdx.y;
    wg = (wg & 7) * 32 + (wg >> 3);
    const int m0 = (wg >> 3) * 128, n0 = (wg & 7) * 128;
    const int grow = lane >> 2, gcol = (lane & 3) * 8;

    floatx4 acc[4][4];
    for (int i = 0; i < 4; i++)
        for (int j = 0; j < 4; j++)
            acc[i][j] = {0.f, 0.f, 0.f, 0.f};

    for (int k0 = 0; k0 < K; k0 += 32) {
        for (int s = 0; s < 2; s++) {
            int r = w * 32 + s * 16;
            async_cp16(&Blds[r * 32], &BT[(size_t)(n0 + r + grow) * K + k0 + gcol]);
            async_cp16(&Alds[r * 32], &A_[(size_t)(m0 + r + grow) * K + k0 + gcol]);
        }
        __syncthreads();

        short8 af[4], bfr[4];
        for (int mt = 0; mt < 4; mt++)
            af[mt] = *(const short8*)(&Alds[(wr * 64 + mt * 16 + cl) * 32 + quad * 8]);
        for (int nt = 0; nt < 4; nt++)
            bfr[nt] = *(const short8*)(&Blds[(wc * 64 + nt * 16 + cl) * 32 + quad * 8]);
        for (int mt = 0; mt < 4; mt++)
            for (int nt = 0; nt < 4; nt++)
                acc[mt][nt] = __builtin_amdgcn_mfma_f32_16x16x32_bf16(
                    af[mt], bfr[nt], acc[mt][nt], 0, 0, 0);
        __syncthreads();
    }

    for (int nt = 0; nt < 4; nt++) {
        int n = n0 + wc * 64 + nt * 16 + cl;
        float bv = bias[n];
        int h = n >> 6, d = n & 63;
        for (int mt = 0; mt < 4; mt++) {
            for (int r = 0; r < 4; r++) {
                int m = m0 + wr * 64 + mt * 16 + quad * 4 + r;
                float v = acc[mt][nt][r] + bv;
                int b = m >> 11, i = m & 2047;
                if (z < 2)
                    C[(((size_t)(b * NHEAD + h)) * L_SEQ + i) * DH + d] = f2b(v);
                else
                    C[(((size_t)(b * NHEAD + h)) * DH + d) * L_SEQ + i] = f2b(v);
            }
        }
    }
}

// ---------------------------------------------------------------------------
// Output GEMM (v16, unchanged).
// ---------------------------------------------------------------------------
__global__ __launch_bounds__(256) void out_gemm(
        const short* __restrict__ A, const short* __restrict__ BT,
        const float* __restrict__ bias, void* __restrict__ C_,
        const int* __restrict__ flagp) {
    const int f32 = *flagp;
    const int K = D_MODEL, N = D_MODEL;
    __shared__ short Alds[128 * 32];
    __shared__ short Blds[64 * 32];
    const int tid = threadIdx.x;
    const int w = tid >> 6, lane = tid & 63, cl = lane & 15, quad = lane >> 4;
    const int wr = w >> 1, wc = w & 1;
    int wg = blockIdx.x + 16 * blockIdx.y;
    wg = (wg & 7) * 64 + (wg >> 3);
    const int m0 = (wg >> 4) * 128, n0 = (wg & 15) * 64;
    const int grow = lane >> 2, gcol = (lane & 3) * 8;

    floatx4 acc[4][2];
    for (int i = 0; i < 4; i++)
        for (int j = 0; j < 2; j++)
            acc[i][j] = {0.f, 0.f, 0.f, 0.f};

    for (int k0 = 0; k0 < K; k0 += 32) {
        for (int s = 0; s < 2; s++) {
            int r = w * 32 + s * 16;
            async_cp16(&Alds[r * 32], &A[(size_t)(m0 + r + grow) * K + k0 + gcol]);
        }
        {
            int r = w * 16;
            async_cp16(&Blds[r * 32], &BT[(size_t)(n0 + r + grow) * K + k0 + gcol]);
        }
        __syncthreads();

        short8 af[4], bfr[2];
        for (int mt = 0; mt < 4; mt++)
            af[mt] = *(const short8*)(&Alds[(wr * 64 + mt * 16 + cl) * 32 + quad * 8]);
        for (int nt = 0; nt < 2; nt++)
            bfr[nt] = *(const short8*)(&Blds[(wc * 32 + nt * 16 + cl) * 32 + quad * 8]);
        for (int mt = 0; mt < 4; mt++)
            for (int nt = 0; nt < 2; nt++)
                acc[mt][nt] = __builtin_amdgcn_mfma_f32_16x16x32_bf16(
                    af[mt], bfr[nt], acc[mt][nt], 0, 0, 0);
        __syncthreads();
    }

    for (int nt = 0; nt < 2; nt++) {
        int n = n0 + wc * 32 + nt * 16 + cl;
        float bv = bias[n];
        for (int mt = 0; mt < 4; mt++) {
            for (int r = 0; r < 4; r++) {
                int m = m0 + wr * 64 + mt * 16 + quad * 4 + r;
                float v = acc[mt][nt][r] + bv;
                if (f32) ((float*)C_)[(size_t)m * N + n] = v;
                else     ((short*)C_)[(size_t)m * N + n] = f2b(v);
            }
        }
    }
}

// ---------------------------------------------------------------------------
// Flash attention v17: v16 body + f32 Pp path (b128 writes / b32 reads,
// pad-92 rows) + b64 P-stores + Pp/P LDS union. 39.9KB LDS, 4 blocks/CU.
// All union accesses memcpy-based (TBAA-safe).
// ---------------------------------------------------------------------------
__global__ __launch_bounds__(256) void attn_kernel(
        const short* __restrict__ Q, const short* __restrict__ K,
        const short* __restrict__ VT, const short* __restrict__ rel,
        short* __restrict__ out) {
    const int tid = threadIdx.x;
    const int w = tid >> 6, lane = tid & 63, cl = lane & 15, quad = lane >> 4;
    // T1 XCD-chunked bijective swizzle (1024 blocks)
    int wg = blockIdx.x + 32 * blockIdx.y;
    wg = (wg & 7) * 128 + (wg >> 3);
    const int bh = wg >> 5, b = bh >> 4, h = bh & 15;
    const int I0 = (wg & 31) * 64;
    const int iw0 = I0 + w * 16;

    const short* Qp = Q + (size_t)bh * L_SEQ * DH;
    const short* Kp = K + (size_t)bh * L_SEQ * DH;
    const short* Vp = VT + (size_t)bh * DH * L_SEQ;

    __shared__ short Klds[64 * 64];          // swizzled, 8KB
    __shared__ short Vtlds[64 * 64];         // swizzled, 8KB
    __shared__ short Ulds[4][16 * PPAD * 2]; // per-wave union: Pp f32 [16][92]
                                             // then P bf16 [16][64]; 23KB

    short* UW = &Ulds[w][0];

    short8 aq[2];
    for (int c = 0; c < 2; c++)
        aq[c] = *(const short8*)(&Qp[(size_t)(iw0 + cl) * DH + c * 32 + quad * 8]);

    const float SCALE2 = 0.125f * 1.44269504088896340736f;  // /sqrt(64)*log2(e)
    const float FMAX = 32.0f;                               // fixed softmax shift

    // clamped-position row constants: q_i . E[0], q_i . E[1024]
    float addlo, addhi;
    {
        floatx4 Dc = {0.f, 0.f, 0.f, 0.f};
        int eidx = (cl == 1) ? 1024 : 0;
        for (int c = 0; c < 2; c++) {
            short8 ae = *(const short8*)(&rel[(size_t)eidx * DH + c * 32 + quad * 8]);
            Dc = __builtin_amdgcn_mfma_f32_16x16x32_bf16(ae, aq[c], Dc, 0, 0, 0);
        }
        float pcl = __shfl(Dc[0], cl, 64);
        float pch = __shfl(Dc[1], cl, 64);
        addlo = fmaf(pcl, SCALE2, -FMAX);
        addhi = fmaf(pch, SCALE2, -FMAX);
    }

    floatx4 O[4];
    for (int dt = 0; dt < 4; dt++) O[dt] = {0.f, 0.f, 0.f, 0.f};
    float lsum = 0.f;

    const int srow = tid >> 2;
    const int spair = (tid & 3) * 2;

    for (int j0 = 0; j0 < L_SEQ; j0 += 64) {
        for (int s = 0; s < 2; s++) {
            int chunk = spair + s;
            int pos = chunk ^ (srow & 7);
            *(short8*)(&Klds[srow * 64 + pos * 8]) =
                *(const short8*)(&Kp[(size_t)(j0 + srow) * DH + chunk * 8]);
            *(short8*)(&Vtlds[srow * 64 + pos * 8]) =
                *(const short8*)(&Vp[(size_t)srow * L_SEQ + j0 + chunk * 8]);
        }
        __syncthreads();

        const bool hi_clamp = (j0 - iw0 - 15) >= 512;
        const bool lo_clamp = (j0 + 63 - iw0) <= -512;
        const bool banded = !(hi_clamp || lo_clamp);
        const float addc = hi_clamp ? addhi : addlo;

        // --- content: S^T[j_loc][i] = K Q^T ---
        floatx4 St[4];
        for (int jt = 0; jt < 4; jt++) {
            St[jt] = {0.f, 0.f, 0.f, 0.f};
            int row = jt * 16 + cl;
            for (int c = 0; c < 2; c++) {
                int pos = ((4 * c + quad) ^ (cl & 7)) * 8;
                short8 bk = *(const short8*)(&Klds[row * 64 + pos]);
                St[jt] = __builtin_amdgcn_mfma_f32_16x16x32_bf16(bk, aq[c], St[jt], 0, 0, 0);
            }
        }

        if (banded) {
            // Pp^T[t][i], t window 0..78
            floatx4 Pt[5];
            for (int pt = 0; pt < 5; pt++) Pt[pt] = {0.f, 0.f, 0.f, 0.f};
            const int base = j0 - iw0 - 15;
            for (int pt = 0; pt < 5; pt++) {
                int raw = pt * 16 + cl + base;
                int idx = (raw < -512 ? -512 : (raw > 512 ? 512 : raw)) + 512;
                const short* ep = rel + (size_t)idx * DH;
                for (int c = 0; c < 2; c++) {
                    short8 be = *(const short8*)(&ep[c * 32 + quad * 8]);
                    Pt[pt] = __builtin_amdgcn_mfma_f32_16x16x32_bf16(be, aq[c], Pt[pt], 0, 0, 0);
                }
            }
            // store transposed [i=cl][t] as RAW F32, one b128 per pt
            // (t = pt*16 + quad*4, t%4==0 -> 16B aligned; pad 92 bank-checked)
            for (int pt = 0; pt < 5; pt++) {
                int t = pt * 16 + quad * 4;
                stf4(&UW[(cl * PPAD + t) * 2], Pt[pt]);
            }
            // wave-internal LDS RAW (memcpy stores may-alias -> ordered)
            for (int jt = 0; jt < 4; jt++)
                for (int r = 0; r < 4; r++) {
                    int t = jt * 16 + quad * 4 + r - cl + 15;   // 0..78
                    float pos = ldf(&UW[(cl * PPAD + t) * 2]);
                    St[jt][r] = fmaf(St[jt][r], SCALE2, fmaf(pos, SCALE2, -FMAX));
                }
        } else {
            for (int jt = 0; jt < 4; jt++)
                for (int r = 0; r < 4; r++)
                    St[jt][r] = fmaf(St[jt][r], SCALE2, addc);
        }

        // --- exp2 + sum ---
        for (int jt = 0; jt < 4; jt++)
            for (int r = 0; r < 4; r++) {
                float p = __builtin_amdgcn_exp2f(St[jt][r]);
                St[jt][r] = p;
                lsum += p;
            }

        // --- P -> per-wave LDS [i=cl][j_loc], swizzled, b64 pairs ---
        // (Pp region is dead; union reuse. pr=0/1 addrs contiguous: +2 shorts)
        for (int jt = 0; jt < 4; jt++) {
            int jl = jt * 16 + quad * 4;
            int addr = cl * 64 + ((jl >> 3) ^ (cl & 7)) * 8 + (jl & 7);
            st4(&UW[addr], pack2(St[jt][0], St[jt][1]),
                           pack2(St[jt][2], St[jt][3]));
        }

        // --- O^T += V^T P^T ---
        for (int c = 0; c < 2; c++) {
            int ppos = ((4 * c + quad) ^ (cl & 7)) * 8;
            short8 bp = *(const short8*)(&UW[cl * 64 + ppos]);
            for (int dt = 0; dt < 4; dt++) {
                int row = dt * 16 + cl;
                int vpos = ((4 * c + quad) ^ (cl & 7)) * 8;
                short8 av = *(const short8*)(&Vtlds[row * 64 + vpos]);
                O[dt] = __builtin_amdgcn_mfma_f32_16x16x32_bf16(av, bp, O[dt], 0, 0, 0);
            }
        }
        __syncthreads();   // before next staging overwrites K/V tiles
    }

    // --- l reduction (once) ---
    lsum += __shfl_xor(lsum, 16, 64);
    lsum += __shfl_xor(lsum, 32, 64);
    float inv = 1.0f / lsum;

    // --- epilogue: O^T*inv -> bf16 transpose via union (b64 pairs) ---
    for (int dt = 0; dt < 4; dt++) {
        int jl = dt * 16 + quad * 4;   // d index
        int addr = cl * 64 + ((jl >> 3) ^ (cl & 7)) * 8 + (jl & 7);
        st4(&UW[addr], pack2(O[dt][0] * inv, O[dt][1] * inv),
                       pack2(O[dt][2] * inv, O[dt][3] * inv));
    }
    // wave-internal; memcpy stores ordered vs short8 reads
    size_t obase = ((size_t)b * L_SEQ + iw0 + cl) * D_MODEL + h * DH;
    for (int s = 0; s < 2; s++) {
        int c2 = quad * 2 + s;
        short8 o = *(const short8*)(&UW[cl * 64 + (c2 ^ (cl & 7)) * 8]);
        *(short8*)(&out[obase + c2 * 8]) = o;
    }
}

// ---------------------------------------------------------------------------
extern "C" void kernel_launch(void* const* d_in, const int* in_sizes, int n_in,
                              void* d_out, int out_size, void* d_ws, size_t ws_size,
                              hipStream_t stream) {
    const void* query = d_in[0];
    const void* key   = d_in[1];
    const void* value = d_in[2];
    const void* wq = d_in[3];  const void* bq = d_in[4];
    const void* wk = d_in[5];  const void* bk = d_in[6];
    const void* wv = d_in[7];  const void* bv = d_in[8];
    const void* wo = d_in[9];  const void* bo = d_in[10];
    const void* rel = d_in[11];

    // v4-proven 40.2MB layout.
    int* flag = (int*)d_ws;
    short* ws = (short*)d_ws + 16;                     // 32B offset
    const size_t WSZ = (size_t)D_MODEL * D_MODEL;      // 1M elems per weight
    const size_t TSZ = (size_t)MROWS * D_MODEL;        // 4M elems per tensor
    short* WT   = ws;                                  // 4 x WSZ (q,k,v,o)
    short* Qw   = ws + 4 * WSZ;
    short* Kw   = Qw + TSZ;
    short* Vtw  = Kw + TSZ;
    short* Attw = Vtw + TSZ;
    float* bias4 = (float*)(Attw + TSZ);               // 4096 fp32
    short* relb  = (short*)(bias4 + 4096);             // 65600 bf16

    // bf16-A scratch for the f32-input path (lifetimes verified, v12).
    short* Cq = (short*)d_out;
    short* Ck = (short*)d_out + TSZ;
    short* Cv = Attw;

    // Host-side dtype from in_sizes[0]; device fallback if ambiguous.
    {
        long qb = (long)in_sizes[0];
        const long FP32B = (long)MROWS * D_MODEL * 4;
        const long BF16B = (long)MROWS * D_MODEL * 2;
        int fhost = (qb == FP32B) ? 1 : (qb == BF16B) ? 0 : -1;
        if (fhost >= 0)
            hipMemsetAsync(flag, fhost, 4, stream);   // 0 or 0x01010101: bool-safe
        else
            detect_dtype<<<1, 256, 0, stream>>>((const unsigned short*)query, flag);
    }

    // fused preprocessing: transpose(4096) + convert(6144) + norm(273)
    prep_all<<<10513, 256, 0, stream>>>(
        wq, wk, wv, wo, bq, bk, bv, bo, rel,
        (const float*)query, (const float*)key, (const float*)value,
        WT, bias4, relb, Cq, Ck, Cv, flag);

    proj_gemm<<<dim3(8, 32, 3), 256, 0, stream>>>(query, key, value,
                                                  Cq, Ck, Cv, WT, bias4,
                                                  Qw, flag);

    attn_kernel<<<dim3(L_SEQ / 64, BH), 256, 0, stream>>>(Qw, Kw, Vtw, relb, Attw);

    out_gemm<<<dim3(16, 32), 256, 0, stream>>>(Attw, WT + 3 * WSZ, bias4 + 3072,
                                               d_out, flag);
}

// Round 10
// 362.112 us; speedup vs baseline: 1.1473x; 1.0356x over previous
//
#include <hip/hip_runtime.h>
#include <hip/hip_bf16.h>

// ---------------------------------------------------------------------------
// RelativeMultiHeadAttention: B=2, L=2048, D=1024, H=16, d=64, MAX_REL=512
// Inputs fp32 (auto-detected vs bf16). Internals bf16 MFMA + fp32 accum.
//
// v18 = v17 (best 375.0us; attn 124.8) + proj_gemm BK=64:
//   - K-loop 32->16 iters: halves the vmcnt(0)/barrier drains (m97
//     structure's ~20% stall), 32 MFMA per barrier-pair instead of 16.
//   - 128B LDS rows -> XOR-swizzled staging (attn-proven rule-21 map:
//     linear DMA dest, pre-swizzled global source chunk p^(r&7); MFMA
//     read slot (ks*4+quad)^(row&7)). LDS 32KB.
//   - attn / out_gemm / prep_all byte-identical to v17 -> Δtotal with
//     attn-constant attributes the GEMM delta cleanly.
// History: attn 141.7(v9) -> 138.5(v16 XCD swz) -> 124.8(v17 VALU trim);
// staging-family (v10-v15) all regressed and is retired.
// ---------------------------------------------------------------------------

typedef __attribute__((ext_vector_type(8))) short short8;   // 8 x bf16 frag
typedef __attribute__((ext_vector_type(4))) float floatx4;

#define L_SEQ 2048
#define D_MODEL 1024
#define NHEAD 16
#define DH 64
#define BH 32           // B*H
#define MROWS 4096      // B*L
#define PPAD 92         // Pp row pad (f32): %4==0 (b128 align)

__device__ inline float b2f(short s) {
    unsigned int u = ((unsigned int)(unsigned short)s) << 16;
    float f; __builtin_memcpy(&f, &u, 4); return f;
}
__device__ inline short f2b(float f) {
    unsigned int u; __builtin_memcpy(&u, &f, 4);
    u += 0x7fffu + ((u >> 16) & 1u);   // round-to-nearest-even
    return (short)(u >> 16);
}
// packed f32x2 -> bf16x2 (v_cvt_pk_bf16_f32 on gfx950)
__device__ inline unsigned int pack2(float a, float b) {
    __hip_bfloat162 h = __float22bfloat162_rn(make_float2(a, b));
    unsigned int u; __builtin_memcpy(&u, &h, 4); return u;
}
// alias-safe 4B store into a short-typed LDS array (ds_write_b32)
__device__ inline void st2(short* p, unsigned int v) {
    __builtin_memcpy(p, &v, 4);
}
// alias-safe 8B store (ds_write_b64): two packed bf16x2 words
__device__ inline void st4(short* p, unsigned int a, unsigned int b) {
    unsigned int v[2] = {a, b}; __builtin_memcpy(p, v, 8);
}
// alias-safe 16B f32x4 store (ds_write_b128)
__device__ inline void stf4(short* p, floatx4 v) {
    __builtin_memcpy(p, &v, 16);
}
// alias-safe f32 load (ds_read_b32)
__device__ inline float ldf(const short* p) {
    float f; __builtin_memcpy(&f, p, 4); return f;
}
// async global->LDS, 16B per lane; lds base must be wave-uniform
__device__ inline void async_cp16(short* lds, const short* g) {
    __builtin_amdgcn_global_load_lds(
        (const __attribute__((address_space(1))) unsigned int*)g,
        (__attribute__((address_space(3))) unsigned int*)lds, 16, 0, 0);
}

// ---------------------------------------------------------------------------
// dtype detector (FALLBACK ONLY): bf16 inf/nan patterns in first 64K shorts.
// ---------------------------------------------------------------------------
__global__ __launch_bounds__(256) void detect_dtype(
        const unsigned short* __restrict__ q, int* __restrict__ flag) {
    __shared__ int s[256];
    int tid = threadIdx.x, cnt = 0;
    for (int i = tid; i < 65536; i += 256)
        if ((q[i] & 0x7F80u) == 0x7F80u) cnt++;
    s[tid] = cnt; __syncthreads();
    for (int st = 128; st; st >>= 1) {
        if (tid < st) s[tid] += s[tid + st];
        __syncthreads();
    }
    if (tid == 0) *flag = (s[0] > 4) ? 1 : 0;   // 1 = inputs are fp32
}

// ---------------------------------------------------------------------------
// prep_all: fused norm_small + transpose4 + convert3 (one launch).
// Roles by block id: [0,4096) transpose, [4096,10240) convert, [10240,10513) norm.
// ---------------------------------------------------------------------------
__global__ __launch_bounds__(256) void prep_all(
        const void* __restrict__ w0, const void* __restrict__ w1,
        const void* __restrict__ w2, const void* __restrict__ w3,
        const void* __restrict__ bq, const void* __restrict__ bk,
        const void* __restrict__ bv, const void* __restrict__ bo,
        const void* __restrict__ rel,
        const float* __restrict__ q, const float* __restrict__ k,
        const float* __restrict__ v,
        short* __restrict__ WT, float* __restrict__ bias4,
        short* __restrict__ relb,
        short* __restrict__ Cq, short* __restrict__ Ck, short* __restrict__ Cv,
        const int* __restrict__ flagp) {
    const int f32 = *flagp;
    const int id = blockIdx.x;
    const int tid = threadIdx.x;

    if (id < 4096) {
        // ---- weight transpose role: 1024 blocks per weight ----
        __shared__ short tile[32][33];
        const int wz = id >> 10, rem = id & 1023;
        const int bx = rem & 31, by = rem >> 5;
        const int tx = tid & 31, ty = tid >> 5;   // (32,8)
        const void* src = (wz == 0) ? w0 : (wz == 1) ? w1 : (wz == 2) ? w2 : w3;
        short* d = WT + (size_t)wz * (D_MODEL * D_MODEL);
        int x = bx * 32 + tx;
        int y0 = by * 32;
        for (int yy = ty; yy < 32; yy += 8) {
            size_t idx = (size_t)(y0 + yy) * D_MODEL + x;
            tile[yy][tx] = f32 ? f2b(((const float*)src)[idx])
                               : ((const short*)src)[idx];
        }
        __syncthreads();
        int x0 = bx * 32;
        for (int yy = ty; yy < 32; yy += 8)
            d[(size_t)(x0 + yy) * D_MODEL + y0 + tx] = tile[tx][yy];
    } else if (id < 10240) {
        // ---- fp32->bf16 convert role: 2048 blocks per tensor ----
        if (!f32) return;
        const int cid = id - 4096;
        const int z = cid >> 11;            // 0..2
        const int bx = cid & 2047;
        const float* src = (z == 0) ? q : (z == 1) ? k : v;
        short* dst = (z == 0) ? Cq : (z == 1) ? Ck : Cv;
        size_t i8 = ((size_t)bx * 256 + tid) * 8;
        float4 f0 = *(const float4*)(&src[i8]);
        float4 f1 = *(const float4*)(&src[i8 + 4]);
        uint4 s;
        s.x = pack2(f0.x, f0.y); s.y = pack2(f0.z, f0.w);
        s.z = pack2(f1.x, f1.y); s.w = pack2(f1.z, f1.w);
        *(uint4*)(&dst[i8]) = s;
    } else {
        // ---- small-tensor canonicalize role: 273 blocks ----
        int t = (id - 10240) * 256 + tid;
        if (t < 4096) {
            const void* src = (t < 1024) ? bq : (t < 2048) ? bk
                            : (t < 3072) ? bv : bo;
            int i = t & 1023;
            bias4[t] = f32 ? ((const float*)src)[i] : b2f(((const short*)src)[i]);
        } else if (t < 4096 + 65600) {
            int i = t - 4096;
            relb[i] = f32 ? f2b(((const float*)rel)[i]) : ((const short*)rel)[i];
        }
    }
}

// ---------------------------------------------------------------------------
// Fused QKV projection GEMM v18: BK=64, XOR-swizzled LDS (128B rows).
// z = 0,1,2.  C = A(4096,1024) @ WT^T + bias.
// Staging: linear DMA dest + pre-swizzled global source (rule 21); read
// slot (ks*4+quad)^(row&7). 16 K-iters (halved barrier drains vs BK=32).
// z 0/1 -> (b,h,l,d) bf16; z=2 -> (b,h,d,l) bf16 (V^T).
// ---------------------------------------------------------------------------
__global__ __launch_bounds__(256) void proj_gemm(
        const void* __restrict__ Aq, const void* __restrict__ Ak,
        const void* __restrict__ Av, const short* __restrict__ Cq,
        const short* __restrict__ Ck, const short* __restrict__ Cv,
        const short* __restrict__ WT, const float* __restrict__ bias4,
        short* __restrict__ Qout, const int* __restrict__ flagp) {
    const int f32 = *flagp;
    const int z = blockIdx.z;
    const short* A_ = f32 ? ((z == 0) ? Cq : (z == 1) ? Ck : Cv)
                          : (const short*)((z == 0) ? Aq : (z == 1) ? Ak : Av);
    const short* BT = WT + (size_t)z * (D_MODEL * D_MODEL);
    const float* bias = bias4 + z * 1024;
    short* C = Qout + (size_t)z * ((size_t)MROWS * D_MODEL);
    const int K = D_MODEL;

    __shared__ short Alds[128 * 64];   // 16KB, XOR-swizzled rows
    __shared__ short Blds[128 * 64];   // 16KB
    const int tid = threadIdx.x;
    const int w = tid >> 6, lane = tid & 63, cl = lane & 15, quad = lane >> 4;
    const int wr = w >> 1, wc = w & 1;
    int wg = blockIdx.x + 8 * blockIdx.y;
    wg = (wg & 7) * 32 + (wg >> 3);
    const int m0 = (wg >> 3) * 128, n0 = (wg & 7) * 128;
    // DMA map: per async, lane l covers row r=base+(l>>3), slot p=l&7;
    // source chunk c = p ^ (r&7)  (base rows are multiples of 8).
    const int lr = lane >> 3;                  // 0..7
    const int lc8 = ((lane & 7) ^ lr) * 8;     // pre-swizzled col (shorts)

    floatx4 acc[4][4];
    for (int i = 0; i < 4; i++)
        for (int j = 0; j < 4; j++)
            acc[i][j] = {0.f, 0.f, 0.f, 0.f};

    for (int k0 = 0; k0 < K; k0 += 64) {
        // stage A and B 128x64 tiles: 4 asyncs each per wave (8 rows/async)
        for (int s = 0; s < 4; s++) {
            int rbase = w * 32 + s * 8;
            async_cp16(&Blds[rbase * 64],
                       &BT[(size_t)(n0 + rbase + lr) * K + k0 + lc8]);
            async_cp16(&Alds[rbase * 64],
                       &A_[(size_t)(m0 + rbase + lr) * K + k0 + lc8]);
        }
        __syncthreads();

        for (int ks = 0; ks < 2; ks++) {
            short8 af[4], bfr[4];
            for (int mt = 0; mt < 4; mt++) {
                int row = wr * 64 + mt * 16 + cl;
                int slot = ((ks * 4 + quad) ^ (row & 7)) * 8;
                af[mt] = *(const short8*)(&Alds[row * 64 + slot]);
            }
            for (int nt = 0; nt < 4; nt++) {
                int row = wc * 64 + nt * 16 + cl;
                int slot = ((ks * 4 + quad) ^ (row & 7)) * 8;
                bfr[nt] = *(const short8*)(&Blds[row * 64 + slot]);
            }
            for (int mt = 0; mt < 4; mt++)
                for (int nt = 0; nt < 4; nt++)
                    acc[mt][nt] = __builtin_amdgcn_mfma_f32_16x16x32_bf16(
                        af[mt], bfr[nt], acc[mt][nt], 0, 0, 0);
        }
        __syncthreads();
    }

    for (int nt = 0; nt < 4; nt++) {
        int n = n0 + wc * 64 + nt * 16 + cl;
        float bv = bias[n];
        int h = n >> 6, d = n & 63;
        for (int mt = 0; mt < 4; mt++) {
            for (int r = 0; r < 4; r++) {
                int m = m0 + wr * 64 + mt * 16 + quad * 4 + r;
                float v = acc[mt][nt][r] + bv;
                int b = m >> 11, i = m & 2047;
                if (z < 2)
                    C[(((size_t)(b * NHEAD + h)) * L_SEQ + i) * DH + d] = f2b(v);
                else
                    C[(((size_t)(b * NHEAD + h)) * DH + d) * L_SEQ + i] = f2b(v);
            }
        }
    }
}

// ---------------------------------------------------------------------------
// Output GEMM (v16/v17, unchanged).
// ---------------------------------------------------------------------------
__global__ __launch_bounds__(256) void out_gemm(
        const short* __restrict__ A, const short* __restrict__ BT,
        const float* __restrict__ bias, void* __restrict__ C_,
        const int* __restrict__ flagp) {
    const int f32 = *flagp;
    const int K = D_MODEL, N = D_MODEL;
    __shared__ short Alds[128 * 32];
    __shared__ short Blds[64 * 32];
    const int tid = threadIdx.x;
    const int w = tid >> 6, lane = tid & 63, cl = lane & 15, quad = lane >> 4;
    const int wr = w >> 1, wc = w & 1;
    int wg = blockIdx.x + 16 * blockIdx.y;
    wg = (wg & 7) * 64 + (wg >> 3);
    const int m0 = (wg >> 4) * 128, n0 = (wg & 15) * 64;
    const int grow = lane >> 2, gcol = (lane & 3) * 8;

    floatx4 acc[4][2];
    for (int i = 0; i < 4; i++)
        for (int j = 0; j < 2; j++)
            acc[i][j] = {0.f, 0.f, 0.f, 0.f};

    for (int k0 = 0; k0 < K; k0 += 32) {
        for (int s = 0; s < 2; s++) {
            int r = w * 32 + s * 16;
            async_cp16(&Alds[r * 32], &A[(size_t)(m0 + r + grow) * K + k0 + gcol]);
        }
        {
            int r = w * 16;
            async_cp16(&Blds[r * 32], &BT[(size_t)(n0 + r + grow) * K + k0 + gcol]);
        }
        __syncthreads();

        short8 af[4], bfr[2];
        for (int mt = 0; mt < 4; mt++)
            af[mt] = *(const short8*)(&Alds[(wr * 64 + mt * 16 + cl) * 32 + quad * 8]);
        for (int nt = 0; nt < 2; nt++)
            bfr[nt] = *(const short8*)(&Blds[(wc * 32 + nt * 16 + cl) * 32 + quad * 8]);
        for (int mt = 0; mt < 4; mt++)
            for (int nt = 0; nt < 2; nt++)
                acc[mt][nt] = __builtin_amdgcn_mfma_f32_16x16x32_bf16(
                    af[mt], bfr[nt], acc[mt][nt], 0, 0, 0);
        __syncthreads();
    }

    for (int nt = 0; nt < 2; nt++) {
        int n = n0 + wc * 32 + nt * 16 + cl;
        float bv = bias[n];
        for (int mt = 0; mt < 4; mt++) {
            for (int r = 0; r < 4; r++) {
                int m = m0 + wr * 64 + mt * 16 + quad * 4 + r;
                float v = acc[mt][nt][r] + bv;
                if (f32) ((float*)C_)[(size_t)m * N + n] = v;
                else     ((short*)C_)[(size_t)m * N + n] = f2b(v);
            }
        }
    }
}

// ---------------------------------------------------------------------------
// Flash attention (v17, unchanged): f32 Pp path, b64 P-stores, Pp/P union,
// XCD swizzle. 39.9KB LDS, 4 blocks/CU. TBAA-safe (memcpy) LDS accesses.
// ---------------------------------------------------------------------------
__global__ __launch_bounds__(256) void attn_kernel(
        const short* __restrict__ Q, const short* __restrict__ K,
        const short* __restrict__ VT, const short* __restrict__ rel,
        short* __restrict__ out) {
    const int tid = threadIdx.x;
    const int w = tid >> 6, lane = tid & 63, cl = lane & 15, quad = lane >> 4;
    int wg = blockIdx.x + 32 * blockIdx.y;
    wg = (wg & 7) * 128 + (wg >> 3);
    const int bh = wg >> 5, b = bh >> 4, h = bh & 15;
    const int I0 = (wg & 31) * 64;
    const int iw0 = I0 + w * 16;

    const short* Qp = Q + (size_t)bh * L_SEQ * DH;
    const short* Kp = K + (size_t)bh * L_SEQ * DH;
    const short* Vp = VT + (size_t)bh * DH * L_SEQ;

    __shared__ short Klds[64 * 64];          // swizzled, 8KB
    __shared__ short Vtlds[64 * 64];         // swizzled, 8KB
    __shared__ short Ulds[4][16 * PPAD * 2]; // per-wave union: Pp f32 / P bf16

    short* UW = &Ulds[w][0];

    short8 aq[2];
    for (int c = 0; c < 2; c++)
        aq[c] = *(const short8*)(&Qp[(size_t)(iw0 + cl) * DH + c * 32 + quad * 8]);

    const float SCALE2 = 0.125f * 1.44269504088896340736f;  // /sqrt(64)*log2(e)
    const float FMAX = 32.0f;                               // fixed softmax shift

    float addlo, addhi;
    {
        floatx4 Dc = {0.f, 0.f, 0.f, 0.f};
        int eidx = (cl == 1) ? 1024 : 0;
        for (int c = 0; c < 2; c++) {
            short8 ae = *(const short8*)(&rel[(size_t)eidx * DH + c * 32 + quad * 8]);
            Dc = __builtin_amdgcn_mfma_f32_16x16x32_bf16(ae, aq[c], Dc, 0, 0, 0);
        }
        float pcl = __shfl(Dc[0], cl, 64);
        float pch = __shfl(Dc[1], cl, 64);
        addlo = fmaf(pcl, SCALE2, -FMAX);
        addhi = fmaf(pch, SCALE2, -FMAX);
    }

    floatx4 O[4];
    for (int dt = 0; dt < 4; dt++) O[dt] = {0.f, 0.f, 0.f, 0.f};
    float lsum = 0.f;

    const int srow = tid >> 2;
    const int spair = (tid & 3) * 2;

    for (int j0 = 0; j0 < L_SEQ; j0 += 64) {
        for (int s = 0; s < 2; s++) {
            int chunk = spair + s;
            int pos = chunk ^ (srow & 7);
            *(short8*)(&Klds[srow * 64 + pos * 8]) =
                *(const short8*)(&Kp[(size_t)(j0 + srow) * DH + chunk * 8]);
            *(short8*)(&Vtlds[srow * 64 + pos * 8]) =
                *(const short8*)(&Vp[(size_t)srow * L_SEQ + j0 + chunk * 8]);
        }
        __syncthreads();

        const bool hi_clamp = (j0 - iw0 - 15) >= 512;
        const bool lo_clamp = (j0 + 63 - iw0) <= -512;
        const bool banded = !(hi_clamp || lo_clamp);
        const float addc = hi_clamp ? addhi : addlo;

        // --- content: S^T[j_loc][i] = K Q^T ---
        floatx4 St[4];
        for (int jt = 0; jt < 4; jt++) {
            St[jt] = {0.f, 0.f, 0.f, 0.f};
            int row = jt * 16 + cl;
            for (int c = 0; c < 2; c++) {
                int pos = ((4 * c + quad) ^ (cl & 7)) * 8;
                short8 bk = *(const short8*)(&Klds[row * 64 + pos]);
                St[jt] = __builtin_amdgcn_mfma_f32_16x16x32_bf16(bk, aq[c], St[jt], 0, 0, 0);
            }
        }

        if (banded) {
            floatx4 Pt[5];
            for (int pt = 0; pt < 5; pt++) Pt[pt] = {0.f, 0.f, 0.f, 0.f};
            const int base = j0 - iw0 - 15;
            for (int pt = 0; pt < 5; pt++) {
                int raw = pt * 16 + cl + base;
                int idx = (raw < -512 ? -512 : (raw > 512 ? 512 : raw)) + 512;
                const short* ep = rel + (size_t)idx * DH;
                for (int c = 0; c < 2; c++) {
                    short8 be = *(const short8*)(&ep[c * 32 + quad * 8]);
                    Pt[pt] = __builtin_amdgcn_mfma_f32_16x16x32_bf16(be, aq[c], Pt[pt], 0, 0, 0);
                }
            }
            for (int pt = 0; pt < 5; pt++) {
                int t = pt * 16 + quad * 4;
                stf4(&UW[(cl * PPAD + t) * 2], Pt[pt]);
            }
            for (int jt = 0; jt < 4; jt++)
                for (int r = 0; r < 4; r++) {
                    int t = jt * 16 + quad * 4 + r - cl + 15;   // 0..78
                    float pos = ldf(&UW[(cl * PPAD + t) * 2]);
                    St[jt][r] = fmaf(St[jt][r], SCALE2, fmaf(pos, SCALE2, -FMAX));
                }
        } else {
            for (int jt = 0; jt < 4; jt++)
                for (int r = 0; r < 4; r++)
                    St[jt][r] = fmaf(St[jt][r], SCALE2, addc);
        }

        // --- exp2 + sum ---
        for (int jt = 0; jt < 4; jt++)
            for (int r = 0; r < 4; r++) {
                float p = __builtin_amdgcn_exp2f(St[jt][r]);
                St[jt][r] = p;
                lsum += p;
            }

        // --- P -> per-wave LDS [i=cl][j_loc], swizzled, b64 pairs ---
        for (int jt = 0; jt < 4; jt++) {
            int jl = jt * 16 + quad * 4;
            int addr = cl * 64 + ((jl >> 3) ^ (cl & 7)) * 8 + (jl & 7);
            st4(&UW[addr], pack2(St[jt][0], St[jt][1]),
                           pack2(St[jt][2], St[jt][3]));
        }

        // --- O^T += V^T P^T ---
        for (int c = 0; c < 2; c++) {
            int ppos = ((4 * c + quad) ^ (cl & 7)) * 8;
            short8 bp = *(const short8*)(&UW[cl * 64 + ppos]);
            for (int dt = 0; dt < 4; dt++) {
                int row = dt * 16 + cl;
                int vpos = ((4 * c + quad) ^ (cl & 7)) * 8;
                short8 av = *(const short8*)(&Vtlds[row * 64 + vpos]);
                O[dt] = __builtin_amdgcn_mfma_f32_16x16x32_bf16(av, bp, O[dt], 0, 0, 0);
            }
        }
        __syncthreads();   // before next staging overwrites K/V tiles
    }

    // --- l reduction (once) ---
    lsum += __shfl_xor(lsum, 16, 64);
    lsum += __shfl_xor(lsum, 32, 64);
    float inv = 1.0f / lsum;

    // --- epilogue: O^T*inv -> bf16 transpose via union (b64 pairs) ---
    for (int dt = 0; dt < 4; dt++) {
        int jl = dt * 16 + quad * 4;   // d index
        int addr = cl * 64 + ((jl >> 3) ^ (cl & 7)) * 8 + (jl & 7);
        st4(&UW[addr], pack2(O[dt][0] * inv, O[dt][1] * inv),
                       pack2(O[dt][2] * inv, O[dt][3] * inv));
    }
    size_t obase = ((size_t)b * L_SEQ + iw0 + cl) * D_MODEL + h * DH;
    for (int s = 0; s < 2; s++) {
        int c2 = quad * 2 + s;
        short8 o = *(const short8*)(&UW[cl * 64 + (c2 ^ (cl & 7)) * 8]);
        *(short8*)(&out[obase + c2 * 8]) = o;
    }
}

// ---------------------------------------------------------------------------
extern "C" void kernel_launch(void* const* d_in, const int* in_sizes, int n_in,
                              void* d_out, int out_size, void* d_ws, size_t ws_size,
                              hipStream_t stream) {
    const void* query = d_in[0];
    const void* key   = d_in[1];
    const void* value = d_in[2];
    const void* wq = d_in[3];  const void* bq = d_in[4];
    const void* wk = d_in[5];  const void* bk = d_in[6];
    const void* wv = d_in[7];  const void* bv = d_in[8];
    const void* wo = d_in[9];  const void* bo = d_in[10];
    const void* rel = d_in[11];

    // v4-proven 40.2MB layout.
    int* flag = (int*)d_ws;
    short* ws = (short*)d_ws + 16;                     // 32B offset
    const size_t WSZ = (size_t)D_MODEL * D_MODEL;      // 1M elems per weight
    const size_t TSZ = (size_t)MROWS * D_MODEL;        // 4M elems per tensor
    short* WT   = ws;                                  // 4 x WSZ (q,k,v,o)
    short* Qw   = ws + 4 * WSZ;
    short* Kw   = Qw + TSZ;
    short* Vtw  = Kw + TSZ;
    short* Attw = Vtw + TSZ;
    float* bias4 = (float*)(Attw + TSZ);               // 4096 fp32
    short* relb  = (short*)(bias4 + 4096);             // 65600 bf16

    // bf16-A scratch for the f32-input path (lifetimes verified, v12).
    short* Cq = (short*)d_out;
    short* Ck = (short*)d_out + TSZ;
    short* Cv = Attw;

    // Host-side dtype from in_sizes[0]; device fallback if ambiguous.
    {
        long qb = (long)in_sizes[0];
        const long FP32B = (long)MROWS * D_MODEL * 4;
        const long BF16B = (long)MROWS * D_MODEL * 2;
        int fhost = (qb == FP32B) ? 1 : (qb == BF16B) ? 0 : -1;
        if (fhost >= 0)
            hipMemsetAsync(flag, fhost, 4, stream);   // 0 or 0x01010101: bool-safe
        else
            detect_dtype<<<1, 256, 0, stream>>>((const unsigned short*)query, flag);
    }

    // fused preprocessing: transpose(4096) + convert(6144) + norm(273)
    prep_all<<<10513, 256, 0, stream>>>(
        wq, wk, wv, wo, bq, bk, bv, bo, rel,
        (const float*)query, (const float*)key, (const float*)value,
        WT, bias4, relb, Cq, Ck, Cv, flag);

    proj_gemm<<<dim3(8, 32, 3), 256, 0, stream>>>(query, key, value,
                                                  Cq, Ck, Cv, WT, bias4,
                                                  Qw, flag);

    attn_kernel<<<dim3(L_SEQ / 64, BH), 256, 0, stream>>>(Qw, Kw, Vtw, relb, Attw);

    out_gemm<<<dim3(16, 32), 256, 0, stream>>>(Attw, WT + 3 * WSZ, bias4 + 3072,
                                               d_out, flag);
}

// Round 11
// 355.120 us; speedup vs baseline: 1.1699x; 1.0197x over previous
//
#include <hip/hip_runtime.h>
#include <hip/hip_bf16.h>

// ---------------------------------------------------------------------------
// RelativeMultiHeadAttention: B=2, L=2048, D=1024, H=16, d=64, MAX_REL=512
// Inputs fp32 (auto-detected vs bf16). Internals bf16 MFMA + fp32 accum.
//
// v19 = v18 (best 362.1us; attn 124.1) + two remainder levers:
//   (a) out_gemm BK=64 port (proj's v18 structure; LDS 24KB) — same
//       halved-barrier mechanism that paid 13us on proj.
//   (b) proj z=2 (V^T) epilogue de-scatter: was 64x 2B stores/lane at 4KB
//       stride (~16x sector waste on 8MB). Now: per-wave 64x64 (d x i)
//       tile bounced through its own 8KB quarter of Alds/Blds (dead after
//       K-loop's final barrier; wave-private -> no new barrier), XOR
//       swizzle (attn-proven), st4 writes / b128 reads -> 8x 16B global
//       stores per lane. memcpy-store + short8-read = v17 TBAA pattern.
// attn / prep_all byte-identical to v18.
// History: attn 141.7(v9)->138.5(v16)->124.8(v17); proj BK64 +13us (v18);
// staging-family v10-v15 retired.
// ---------------------------------------------------------------------------

typedef __attribute__((ext_vector_type(8))) short short8;   // 8 x bf16 frag
typedef __attribute__((ext_vector_type(4))) float floatx4;

#define L_SEQ 2048
#define D_MODEL 1024
#define NHEAD 16
#define DH 64
#define BH 32           // B*H
#define MROWS 4096      // B*L
#define PPAD 92         // Pp row pad (f32): %4==0 (b128 align)

__device__ inline float b2f(short s) {
    unsigned int u = ((unsigned int)(unsigned short)s) << 16;
    float f; __builtin_memcpy(&f, &u, 4); return f;
}
__device__ inline short f2b(float f) {
    unsigned int u; __builtin_memcpy(&u, &f, 4);
    u += 0x7fffu + ((u >> 16) & 1u);   // round-to-nearest-even
    return (short)(u >> 16);
}
// packed f32x2 -> bf16x2 (v_cvt_pk_bf16_f32 on gfx950)
__device__ inline unsigned int pack2(float a, float b) {
    __hip_bfloat162 h = __float22bfloat162_rn(make_float2(a, b));
    unsigned int u; __builtin_memcpy(&u, &h, 4); return u;
}
// alias-safe 4B store into a short-typed LDS array (ds_write_b32)
__device__ inline void st2(short* p, unsigned int v) {
    __builtin_memcpy(p, &v, 4);
}
// alias-safe 8B store (ds_write_b64): two packed bf16x2 words
__device__ inline void st4(short* p, unsigned int a, unsigned int b) {
    unsigned int v[2] = {a, b}; __builtin_memcpy(p, v, 8);
}
// alias-safe 16B f32x4 store (ds_write_b128)
__device__ inline void stf4(short* p, floatx4 v) {
    __builtin_memcpy(p, &v, 16);
}
// alias-safe f32 load (ds_read_b32)
__device__ inline float ldf(const short* p) {
    float f; __builtin_memcpy(&f, p, 4); return f;
}
// async global->LDS, 16B per lane; lds base must be wave-uniform
__device__ inline void async_cp16(short* lds, const short* g) {
    __builtin_amdgcn_global_load_lds(
        (const __attribute__((address_space(1))) unsigned int*)g,
        (__attribute__((address_space(3))) unsigned int*)lds, 16, 0, 0);
}

// ---------------------------------------------------------------------------
// dtype detector (FALLBACK ONLY): bf16 inf/nan patterns in first 64K shorts.
// ---------------------------------------------------------------------------
__global__ __launch_bounds__(256) void detect_dtype(
        const unsigned short* __restrict__ q, int* __restrict__ flag) {
    __shared__ int s[256];
    int tid = threadIdx.x, cnt = 0;
    for (int i = tid; i < 65536; i += 256)
        if ((q[i] & 0x7F80u) == 0x7F80u) cnt++;
    s[tid] = cnt; __syncthreads();
    for (int st = 128; st; st >>= 1) {
        if (tid < st) s[tid] += s[tid + st];
        __syncthreads();
    }
    if (tid == 0) *flag = (s[0] > 4) ? 1 : 0;   // 1 = inputs are fp32
}

// ---------------------------------------------------------------------------
// prep_all: fused norm_small + transpose4 + convert3 (one launch).
// Roles by block id: [0,4096) transpose, [4096,10240) convert, [10240,10513) norm.
// ---------------------------------------------------------------------------
__global__ __launch_bounds__(256) void prep_all(
        const void* __restrict__ w0, const void* __restrict__ w1,
        const void* __restrict__ w2, const void* __restrict__ w3,
        const void* __restrict__ bq, const void* __restrict__ bk,
        const void* __restrict__ bv, const void* __restrict__ bo,
        const void* __restrict__ rel,
        const float* __restrict__ q, const float* __restrict__ k,
        const float* __restrict__ v,
        short* __restrict__ WT, float* __restrict__ bias4,
        short* __restrict__ relb,
        short* __restrict__ Cq, short* __restrict__ Ck, short* __restrict__ Cv,
        const int* __restrict__ flagp) {
    const int f32 = *flagp;
    const int id = blockIdx.x;
    const int tid = threadIdx.x;

    if (id < 4096) {
        // ---- weight transpose role: 1024 blocks per weight ----
        __shared__ short tile[32][33];
        const int wz = id >> 10, rem = id & 1023;
        const int bx = rem & 31, by = rem >> 5;
        const int tx = tid & 31, ty = tid >> 5;   // (32,8)
        const void* src = (wz == 0) ? w0 : (wz == 1) ? w1 : (wz == 2) ? w2 : w3;
        short* d = WT + (size_t)wz * (D_MODEL * D_MODEL);
        int x = bx * 32 + tx;
        int y0 = by * 32;
        for (int yy = ty; yy < 32; yy += 8) {
            size_t idx = (size_t)(y0 + yy) * D_MODEL + x;
            tile[yy][tx] = f32 ? f2b(((const float*)src)[idx])
                               : ((const short*)src)[idx];
        }
        __syncthreads();
        int x0 = bx * 32;
        for (int yy = ty; yy < 32; yy += 8)
            d[(size_t)(x0 + yy) * D_MODEL + y0 + tx] = tile[tx][yy];
    } else if (id < 10240) {
        // ---- fp32->bf16 convert role: 2048 blocks per tensor ----
        if (!f32) return;
        const int cid = id - 4096;
        const int z = cid >> 11;            // 0..2
        const int bx = cid & 2047;
        const float* src = (z == 0) ? q : (z == 1) ? k : v;
        short* dst = (z == 0) ? Cq : (z == 1) ? Ck : Cv;
        size_t i8 = ((size_t)bx * 256 + tid) * 8;
        float4 f0 = *(const float4*)(&src[i8]);
        float4 f1 = *(const float4*)(&src[i8 + 4]);
        uint4 s;
        s.x = pack2(f0.x, f0.y); s.y = pack2(f0.z, f0.w);
        s.z = pack2(f1.x, f1.y); s.w = pack2(f1.z, f1.w);
        *(uint4*)(&dst[i8]) = s;
    } else {
        // ---- small-tensor canonicalize role: 273 blocks ----
        int t = (id - 10240) * 256 + tid;
        if (t < 4096) {
            const void* src = (t < 1024) ? bq : (t < 2048) ? bk
                            : (t < 3072) ? bv : bo;
            int i = t & 1023;
            bias4[t] = f32 ? ((const float*)src)[i] : b2f(((const short*)src)[i]);
        } else if (t < 4096 + 65600) {
            int i = t - 4096;
            relb[i] = f32 ? f2b(((const float*)rel)[i]) : ((const short*)rel)[i];
        }
    }
}

// ---------------------------------------------------------------------------
// Fused QKV projection GEMM v19: BK=64, XOR-swizzled LDS (128B rows).
// z = 0,1,2.  C = A(4096,1024) @ WT^T + bias.
// z 0/1 -> (b,h,l,d) bf16 (direct stores, 32B-coalesced);
// z=2  -> (b,h,d,l) bf16 (V^T) via per-wave LDS transpose (de-scattered).
// ---------------------------------------------------------------------------
__global__ __launch_bounds__(256) void proj_gemm(
        const void* __restrict__ Aq, const void* __restrict__ Ak,
        const void* __restrict__ Av, const short* __restrict__ Cq,
        const short* __restrict__ Ck, const short* __restrict__ Cv,
        const short* __restrict__ WT, const float* __restrict__ bias4,
        short* __restrict__ Qout, const int* __restrict__ flagp) {
    const int f32 = *flagp;
    const int z = blockIdx.z;
    const short* A_ = f32 ? ((z == 0) ? Cq : (z == 1) ? Ck : Cv)
                          : (const short*)((z == 0) ? Aq : (z == 1) ? Ak : Av);
    const short* BT = WT + (size_t)z * (D_MODEL * D_MODEL);
    const float* bias = bias4 + z * 1024;
    short* C = Qout + (size_t)z * ((size_t)MROWS * D_MODEL);
    const int K = D_MODEL;

    __shared__ short Alds[128 * 64];   // 16KB, XOR-swizzled rows
    __shared__ short Blds[128 * 64];   // 16KB
    const int tid = threadIdx.x;
    const int w = tid >> 6, lane = tid & 63, cl = lane & 15, quad = lane >> 4;
    const int wr = w >> 1, wc = w & 1;
    int wg = blockIdx.x + 8 * blockIdx.y;
    wg = (wg & 7) * 32 + (wg >> 3);
    const int m0 = (wg >> 3) * 128, n0 = (wg & 7) * 128;
    const int lr = lane >> 3;                  // 0..7
    const int lc8 = ((lane & 7) ^ lr) * 8;     // pre-swizzled col (shorts)

    floatx4 acc[4][4];
    for (int i = 0; i < 4; i++)
        for (int j = 0; j < 4; j++)
            acc[i][j] = {0.f, 0.f, 0.f, 0.f};

    for (int k0 = 0; k0 < K; k0 += 64) {
        for (int s = 0; s < 4; s++) {
            int rbase = w * 32 + s * 8;
            async_cp16(&Blds[rbase * 64],
                       &BT[(size_t)(n0 + rbase + lr) * K + k0 + lc8]);
            async_cp16(&Alds[rbase * 64],
                       &A_[(size_t)(m0 + rbase + lr) * K + k0 + lc8]);
        }
        __syncthreads();

        for (int ks = 0; ks < 2; ks++) {
            short8 af[4], bfr[4];
            for (int mt = 0; mt < 4; mt++) {
                int row = wr * 64 + mt * 16 + cl;
                int slot = ((ks * 4 + quad) ^ (row & 7)) * 8;
                af[mt] = *(const short8*)(&Alds[row * 64 + slot]);
            }
            for (int nt = 0; nt < 4; nt++) {
                int row = wc * 64 + nt * 16 + cl;
                int slot = ((ks * 4 + quad) ^ (row & 7)) * 8;
                bfr[nt] = *(const short8*)(&Blds[row * 64 + slot]);
            }
            for (int mt = 0; mt < 4; mt++)
                for (int nt = 0; nt < 4; nt++)
                    acc[mt][nt] = __builtin_amdgcn_mfma_f32_16x16x32_bf16(
                        af[mt], bfr[nt], acc[mt][nt], 0, 0, 0);
        }
        __syncthreads();
    }

    if (z < 2) {
        // direct stores: lanes 0-15 cover 16 consecutive d -> 32B runs
        for (int nt = 0; nt < 4; nt++) {
            int n = n0 + wc * 64 + nt * 16 + cl;
            float bv = bias[n];
            int h = n >> 6, d = n & 63;
            for (int mt = 0; mt < 4; mt++) {
                for (int r = 0; r < 4; r++) {
                    int m = m0 + wr * 64 + mt * 16 + quad * 4 + r;
                    float v = acc[mt][nt][r] + bv;
                    int b = m >> 11, i = m & 2047;
                    C[(((size_t)(b * NHEAD + h)) * L_SEQ + i) * DH + d] = f2b(v);
                }
            }
        }
    } else {
        // V^T epilogue: per-wave 64x64 (d x i) LDS transpose, XOR-swizzled.
        // Alds/Blds are dead (final loop barrier passed); regions wave-private
        // so no extra barrier. st4 memcpy writes; short8 memcpy reads (TBAA).
        short* Wt = (w < 2) ? &Alds[w * 4096] : &Blds[(w - 2) * 4096];
        for (int nt = 0; nt < 4; nt++) {
            int d = nt * 16 + cl;                       // 0..63
            float bv = bias[n0 + wc * 64 + nt * 16 + cl];
            for (int mt = 0; mt < 4; mt++) {
                int ib = mt * 16 + quad * 4;            // i_local, %4==0
                int addr = d * 64 + (((ib >> 3) ^ (d & 7)) << 3) + (ib & 7);
                st4(&Wt[addr], pack2(acc[mt][nt][0] + bv, acc[mt][nt][1] + bv),
                               pack2(acc[mt][nt][2] + bv, acc[mt][nt][3] + bv));
            }
        }
        int hh = (n0 + wc * 64) >> 6;                   // head of this wave
        int mA = m0 + wr * 64;                          // 64-aligned, 1 batch
        int bb = mA >> 11, i0 = mA & 2047;
        size_t cb = (((size_t)(bb * NHEAD + hh)) * DH + lane) * L_SEQ + i0;
        for (int c = 0; c < 8; c++) {
            int slot = ((c ^ (lane & 7)) << 3);
            short8 o; __builtin_memcpy(&o, &Wt[lane * 64 + slot], 16);
            *(short8*)(&C[cb + c * 8]) = o;             // 16B per store
        }
    }
}

// ---------------------------------------------------------------------------
// Output GEMM v19: BK=64 (proj structure), XOR-swizzled LDS. 24KB.
// C(4096,1024) = A @ WT^T + bias.  128x64 tile.
// ---------------------------------------------------------------------------
__global__ __launch_bounds__(256) void out_gemm(
        const short* __restrict__ A, const short* __restrict__ BT,
        const float* __restrict__ bias, void* __restrict__ C_,
        const int* __restrict__ flagp) {
    const int f32 = *flagp;
    const int K = D_MODEL, N = D_MODEL;
    __shared__ short Alds[128 * 64];   // 16KB
    __shared__ short Blds[64 * 64];    // 8KB
    const int tid = threadIdx.x;
    const int w = tid >> 6, lane = tid & 63, cl = lane & 15, quad = lane >> 4;
    const int wr = w >> 1, wc = w & 1;
    int wg = blockIdx.x + 16 * blockIdx.y;
    wg = (wg & 7) * 64 + (wg >> 3);
    const int m0 = (wg >> 4) * 128, n0 = (wg & 15) * 64;
    const int lr = lane >> 3;
    const int lc8 = ((lane & 7) ^ lr) * 8;

    floatx4 acc[4][2];
    for (int i = 0; i < 4; i++)
        for (int j = 0; j < 2; j++)
            acc[i][j] = {0.f, 0.f, 0.f, 0.f};

    for (int k0 = 0; k0 < K; k0 += 64) {
        for (int s = 0; s < 4; s++) {
            int rbase = w * 32 + s * 8;
            async_cp16(&Alds[rbase * 64],
                       &A[(size_t)(m0 + rbase + lr) * K + k0 + lc8]);
        }
        for (int s = 0; s < 2; s++) {
            int rbase = w * 16 + s * 8;
            async_cp16(&Blds[rbase * 64],
                       &BT[(size_t)(n0 + rbase + lr) * K + k0 + lc8]);
        }
        __syncthreads();

        for (int ks = 0; ks < 2; ks++) {
            short8 af[4], bfr[2];
            for (int mt = 0; mt < 4; mt++) {
                int row = wr * 64 + mt * 16 + cl;
                int slot = ((ks * 4 + quad) ^ (row & 7)) * 8;
                af[mt] = *(const short8*)(&Alds[row * 64 + slot]);
            }
            for (int nt = 0; nt < 2; nt++) {
                int row = wc * 32 + nt * 16 + cl;
                int slot = ((ks * 4 + quad) ^ (row & 7)) * 8;
                bfr[nt] = *(const short8*)(&Blds[row * 64 + slot]);
            }
            for (int mt = 0; mt < 4; mt++)
                for (int nt = 0; nt < 2; nt++)
                    acc[mt][nt] = __builtin_amdgcn_mfma_f32_16x16x32_bf16(
                        af[mt], bfr[nt], acc[mt][nt], 0, 0, 0);
        }
        __syncthreads();
    }

    for (int nt = 0; nt < 2; nt++) {
        int n = n0 + wc * 32 + nt * 16 + cl;
        float bv = bias[n];
        for (int mt = 0; mt < 4; mt++) {
            for (int r = 0; r < 4; r++) {
                int m = m0 + wr * 64 + mt * 16 + quad * 4 + r;
                float v = acc[mt][nt][r] + bv;
                if (f32) ((float*)C_)[(size_t)m * N + n] = v;
                else     ((short*)C_)[(size_t)m * N + n] = f2b(v);
            }
        }
    }
}

// ---------------------------------------------------------------------------
// Flash attention (v17/v18, unchanged): f32 Pp path, b64 P-stores, Pp/P
// union, XCD swizzle. 39.9KB LDS, 4 blocks/CU. TBAA-safe LDS accesses.
// ---------------------------------------------------------------------------
__global__ __launch_bounds__(256) void attn_kernel(
        const short* __restrict__ Q, const short* __restrict__ K,
        const short* __restrict__ VT, const short* __restrict__ rel,
        short* __restrict__ out) {
    const int tid = threadIdx.x;
    const int w = tid >> 6, lane = tid & 63, cl = lane & 15, quad = lane >> 4;
    int wg = blockIdx.x + 32 * blockIdx.y;
    wg = (wg & 7) * 128 + (wg >> 3);
    const int bh = wg >> 5, b = bh >> 4, h = bh & 15;
    const int I0 = (wg & 31) * 64;
    const int iw0 = I0 + w * 16;

    const short* Qp = Q + (size_t)bh * L_SEQ * DH;
    const short* Kp = K + (size_t)bh * L_SEQ * DH;
    const short* Vp = VT + (size_t)bh * DH * L_SEQ;

    __shared__ short Klds[64 * 64];          // swizzled, 8KB
    __shared__ short Vtlds[64 * 64];         // swizzled, 8KB
    __shared__ short Ulds[4][16 * PPAD * 2]; // per-wave union: Pp f32 / P bf16

    short* UW = &Ulds[w][0];

    short8 aq[2];
    for (int c = 0; c < 2; c++)
        aq[c] = *(const short8*)(&Qp[(size_t)(iw0 + cl) * DH + c * 32 + quad * 8]);

    const float SCALE2 = 0.125f * 1.44269504088896340736f;  // /sqrt(64)*log2(e)
    const float FMAX = 32.0f;                               // fixed softmax shift

    float addlo, addhi;
    {
        floatx4 Dc = {0.f, 0.f, 0.f, 0.f};
        int eidx = (cl == 1) ? 1024 : 0;
        for (int c = 0; c < 2; c++) {
            short8 ae = *(const short8*)(&rel[(size_t)eidx * DH + c * 32 + quad * 8]);
            Dc = __builtin_amdgcn_mfma_f32_16x16x32_bf16(ae, aq[c], Dc, 0, 0, 0);
        }
        float pcl = __shfl(Dc[0], cl, 64);
        float pch = __shfl(Dc[1], cl, 64);
        addlo = fmaf(pcl, SCALE2, -FMAX);
        addhi = fmaf(pch, SCALE2, -FMAX);
    }

    floatx4 O[4];
    for (int dt = 0; dt < 4; dt++) O[dt] = {0.f, 0.f, 0.f, 0.f};
    float lsum = 0.f;

    const int srow = tid >> 2;
    const int spair = (tid & 3) * 2;

    for (int j0 = 0; j0 < L_SEQ; j0 += 64) {
        for (int s = 0; s < 2; s++) {
            int chunk = spair + s;
            int pos = chunk ^ (srow & 7);
            *(short8*)(&Klds[srow * 64 + pos * 8]) =
                *(const short8*)(&Kp[(size_t)(j0 + srow) * DH + chunk * 8]);
            *(short8*)(&Vtlds[srow * 64 + pos * 8]) =
                *(const short8*)(&Vp[(size_t)srow * L_SEQ + j0 + chunk * 8]);
        }
        __syncthreads();

        const bool hi_clamp = (j0 - iw0 - 15) >= 512;
        const bool lo_clamp = (j0 + 63 - iw0) <= -512;
        const bool banded = !(hi_clamp || lo_clamp);
        const float addc = hi_clamp ? addhi : addlo;

        // --- content: S^T[j_loc][i] = K Q^T ---
        floatx4 St[4];
        for (int jt = 0; jt < 4; jt++) {
            St[jt] = {0.f, 0.f, 0.f, 0.f};
            int row = jt * 16 + cl;
            for (int c = 0; c < 2; c++) {
                int pos = ((4 * c + quad) ^ (cl & 7)) * 8;
                short8 bk = *(const short8*)(&Klds[row * 64 + pos]);
                St[jt] = __builtin_amdgcn_mfma_f32_16x16x32_bf16(bk, aq[c], St[jt], 0, 0, 0);
            }
        }

        if (banded) {
            floatx4 Pt[5];
            for (int pt = 0; pt < 5; pt++) Pt[pt] = {0.f, 0.f, 0.f, 0.f};
            const int base = j0 - iw0 - 15;
            for (int pt = 0; pt < 5; pt++) {
                int raw = pt * 16 + cl + base;
                int idx = (raw < -512 ? -512 : (raw > 512 ? 512 : raw)) + 512;
                const short* ep = rel + (size_t)idx * DH;
                for (int c = 0; c < 2; c++) {
                    short8 be = *(const short8*)(&ep[c * 32 + quad * 8]);
                    Pt[pt] = __builtin_amdgcn_mfma_f32_16x16x32_bf16(be, aq[c], Pt[pt], 0, 0, 0);
                }
            }
            for (int pt = 0; pt < 5; pt++) {
                int t = pt * 16 + quad * 4;
                stf4(&UW[(cl * PPAD + t) * 2], Pt[pt]);
            }
            for (int jt = 0; jt < 4; jt++)
                for (int r = 0; r < 4; r++) {
                    int t = jt * 16 + quad * 4 + r - cl + 15;   // 0..78
                    float pos = ldf(&UW[(cl * PPAD + t) * 2]);
                    St[jt][r] = fmaf(St[jt][r], SCALE2, fmaf(pos, SCALE2, -FMAX));
                }
        } else {
            for (int jt = 0; jt < 4; jt++)
                for (int r = 0; r < 4; r++)
                    St[jt][r] = fmaf(St[jt][r], SCALE2, addc);
        }

        // --- exp2 + sum ---
        for (int jt = 0; jt < 4; jt++)
            for (int r = 0; r < 4; r++) {
                float p = __builtin_amdgcn_exp2f(St[jt][r]);
                St[jt][r] = p;
                lsum += p;
            }

        // --- P -> per-wave LDS [i=cl][j_loc], swizzled, b64 pairs ---
        for (int jt = 0; jt < 4; jt++) {
            int jl = jt * 16 + quad * 4;
            int addr = cl * 64 + ((jl >> 3) ^ (cl & 7)) * 8 + (jl & 7);
            st4(&UW[addr], pack2(St[jt][0], St[jt][1]),
                           pack2(St[jt][2], St[jt][3]));
        }

        // --- O^T += V^T P^T ---
        for (int c = 0; c < 2; c++) {
            int ppos = ((4 * c + quad) ^ (cl & 7)) * 8;
            short8 bp = *(const short8*)(&UW[cl * 64 + ppos]);
            for (int dt = 0; dt < 4; dt++) {
                int row = dt * 16 + cl;
                int vpos = ((4 * c + quad) ^ (cl & 7)) * 8;
                short8 av = *(const short8*)(&Vtlds[row * 64 + vpos]);
                O[dt] = __builtin_amdgcn_mfma_f32_16x16x32_bf16(av, bp, O[dt], 0, 0, 0);
            }
        }
        __syncthreads();   // before next staging overwrites K/V tiles
    }

    // --- l reduction (once) ---
    lsum += __shfl_xor(lsum, 16, 64);
    lsum += __shfl_xor(lsum, 32, 64);
    float inv = 1.0f / lsum;

    // --- epilogue: O^T*inv -> bf16 transpose via union (b64 pairs) ---
    for (int dt = 0; dt < 4; dt++) {
        int jl = dt * 16 + quad * 4;   // d index
        int addr = cl * 64 + ((jl >> 3) ^ (cl & 7)) * 8 + (jl & 7);
        st4(&UW[addr], pack2(O[dt][0] * inv, O[dt][1] * inv),
                       pack2(O[dt][2] * inv, O[dt][3] * inv));
    }
    size_t obase = ((size_t)b * L_SEQ + iw0 + cl) * D_MODEL + h * DH;
    for (int s = 0; s < 2; s++) {
        int c2 = quad * 2 + s;
        short8 o = *(const short8*)(&UW[cl * 64 + (c2 ^ (cl & 7)) * 8]);
        *(short8*)(&out[obase + c2 * 8]) = o;
    }
}

// ---------------------------------------------------------------------------
extern "C" void kernel_launch(void* const* d_in, const int* in_sizes, int n_in,
                              void* d_out, int out_size, void* d_ws, size_t ws_size,
                              hipStream_t stream) {
    const void* query = d_in[0];
    const void* key   = d_in[1];
    const void* value = d_in[2];
    const void* wq = d_in[3];  const void* bq = d_in[4];
    const void* wk = d_in[5];  const void* bk = d_in[6];
    const void* wv = d_in[7];  const void* bv = d_in[8];
    const void* wo = d_in[9];  const void* bo = d_in[10];
    const void* rel = d_in[11];

    // v4-proven 40.2MB layout.
    int* flag = (int*)d_ws;
    short* ws = (short*)d_ws + 16;                     // 32B offset
    const size_t WSZ = (size_t)D_MODEL * D_MODEL;      // 1M elems per weight
    const size_t TSZ = (size_t)MROWS * D_MODEL;        // 4M elems per tensor
    short* WT   = ws;                                  // 4 x WSZ (q,k,v,o)
    short* Qw   = ws + 4 * WSZ;
    short* Kw   = Qw + TSZ;
    short* Vtw  = Kw + TSZ;
    short* Attw = Vtw + TSZ;
    float* bias4 = (float*)(Attw + TSZ);               // 4096 fp32
    short* relb  = (short*)(bias4 + 4096);             // 65600 bf16

    // bf16-A scratch for the f32-input path (lifetimes verified, v12).
    short* Cq = (short*)d_out;
    short* Ck = (short*)d_out + TSZ;
    short* Cv = Attw;

    // Host-side dtype from in_sizes[0]; device fallback if ambiguous.
    {
        long qb = (long)in_sizes[0];
        const long FP32B = (long)MROWS * D_MODEL * 4;
        const long BF16B = (long)MROWS * D_MODEL * 2;
        int fhost = (qb == FP32B) ? 1 : (qb == BF16B) ? 0 : -1;
        if (fhost >= 0)
            hipMemsetAsync(flag, fhost, 4, stream);   // 0 or 0x01010101: bool-safe
        else
            detect_dtype<<<1, 256, 0, stream>>>((const unsigned short*)query, flag);
    }

    // fused preprocessing: transpose(4096) + convert(6144) + norm(273)
    prep_all<<<10513, 256, 0, stream>>>(
        wq, wk, wv, wo, bq, bk, bv, bo, rel,
        (const float*)query, (const float*)key, (const float*)value,
        WT, bias4, relb, Cq, Ck, Cv, flag);

    proj_gemm<<<dim3(8, 32, 3), 256, 0, stream>>>(query, key, value,
                                                  Cq, Ck, Cv, WT, bias4,
                                                  Qw, flag);

    attn_kernel<<<dim3(L_SEQ / 64, BH), 256, 0, stream>>>(Qw, Kw, Vtw, relb, Attw);

    out_gemm<<<dim3(16, 32), 256, 0, stream>>>(Attw, WT + 3 * WSZ, bias4 + 3072,
                                               d_out, flag);
}